// Round 6
// baseline (25325.223 us; speedup 1.0000x reference)
//
#include <hip/hip_runtime.h>
#include <stdint.h>

// Problem constants
#define BB   64
#define TT   512
#define HT   256
#define OO   128
#define GATES 1024   // 4*H

// lstm weight-persistence split (units of "kq" = 4 consecutive k values;
// per kq per thread: 2 float4 = rows (2t,2t+1) x k[4u..4u+3]; 16 KB/unit)
// Sized for the 128-VGPR budget the allocator actually grants 512-thread
// blocks (R3/R4: anything bigger spills to scratch, 10 GB/dispatch thrash).
#define UREG 10                    // kq in VGPRs: 20 f4 = 40 VGPR/lane
#define ULDS 9                     // kq in LDS: 144 KB
#define USTR (64 - UREG - ULDS)    // 45 kq streamed from L2 each step (720 KB)

// pipeline constants
#define CCH  16                    // steps per chunk
#define NCH  (TT / CCH)            // 32 chunks
#define RING 6                     // ring slots per batch (Ag1 chunks)

__device__ __forceinline__ float sigmoidf_(float x) {
    return 1.0f / (1.0f + __expf(-x));
}

// ---------------------------------------------------------------------------
// Embedding gather + decoder_action output
__global__ __launch_bounds__(256) void embed_kernel(
    const int* __restrict__ actions, const float* __restrict__ emb_table,
    float* __restrict__ X, float* __restrict__ dact)
{
    int row = blockIdx.x;
    int t = row & (TT - 1);
    int id = (t == 0) ? 0 : actions[row - 1];
    X[(int64_t)row * HT + threadIdx.x] = emb_table[(int64_t)id * HT + threadIdx.x];
    if (threadIdx.x == 0) dact[row] = (float)actions[row];
}

// ---------------------------------------------------------------------------
// Repack Whh into the lstm load layout:
// Wpk4[l*65536 + (u*2+f)*512 + t] = float4 of Whh[l][2t+f][4u .. 4u+3]
__global__ __launch_bounds__(256) void repack_whh_kernel(
    const float* __restrict__ Whh, float4* __restrict__ Wpk4)
{
    int fl = blockIdx.x * 256 + threadIdx.x;   // 0..131071
    int l   = fl >> 16;
    int rem = fl & 65535;
    int uf  = rem >> 9;          // 0..127
    int t   = rem & 511;
    int u   = uf >> 1;
    int f   = uf & 1;
    Wpk4[fl] = *(const float4*)(Whh + (int64_t)l * (GATES * HT)
                                    + (int64_t)(2 * t + f) * HT + 4 * u);
}

// Transpose Wih layer 1: WihT[k*1024 + n] = Wih[1][n][k].  262144 elems.
__global__ __launch_bounds__(256) void transpose_wih1_kernel(
    const float* __restrict__ Wih, float* __restrict__ WihT)
{
    int idx = blockIdx.x * 256 + threadIdx.x;   // 0..262143
    int k = idx >> 10;
    int n = idx & 1023;
    WihT[idx] = Wih[(int64_t)GATES * HT + (int64_t)n * HT + k];
}

// zero the pipeline flags (ws is re-poisoned to 0xAA before every launch)
__global__ __launch_bounds__(256) void zero_kernel(int* __restrict__ p, int n)
{
    int i = blockIdx.x * 256 + threadIdx.x;
    if (i < n) p[i] = 0;
}

// ---------------------------------------------------------------------------
// Generic fp32 tiled GEMM: C = act( A @ op(B) + bias1 + bias2 )
// BM=BN=128, BK=16, 256 threads, 8x8 per thread. Dims divisible.
template<bool TRANS_B, int ACT>
__global__ __launch_bounds__(256) void gemm128_kernel(
    const float* __restrict__ A, const float* __restrict__ Bm,
    float* __restrict__ C,
    int K, int lda, int ldb, int ldc,
    int64_t sA, int64_t sB, int64_t sC,
    const float* __restrict__ bias1, const float* __restrict__ bias2)
{
    constexpr int BM = 128, BN = 128, BK = 16;
    __shared__ __align__(16) float As[BK][BM + 4];
    __shared__ __align__(16) float Bs[BK][BN + 4];

    const int tid = threadIdx.x;
    const int m0 = blockIdx.y * BM;
    const int n0 = blockIdx.x * BN;
    A  += (int64_t)blockIdx.z * sA;
    Bm += (int64_t)blockIdx.z * sB;
    C  += (int64_t)blockIdx.z * sC;

    const int tm = tid & 15;
    const int tn = tid >> 4;

    float acc[8][8] = {};

    for (int k0 = 0; k0 < K; k0 += BK) {
        #pragma unroll
        for (int i = 0; i < 2; i++) {
            int idx = tid + i * 256;
            int ar = idx >> 2;
            int ak = (idx & 3) * 4;
            const float4 v = *(const float4*)(A + (int64_t)(m0 + ar) * lda + k0 + ak);
            As[ak + 0][ar] = v.x; As[ak + 1][ar] = v.y;
            As[ak + 2][ar] = v.z; As[ak + 3][ar] = v.w;
        }
        if (TRANS_B) {
            #pragma unroll
            for (int i = 0; i < 2; i++) {
                int idx = tid + i * 256;
                int br = idx >> 2;
                int bk = (idx & 3) * 4;
                const float4 v = *(const float4*)(Bm + (int64_t)(n0 + br) * ldb + k0 + bk);
                Bs[bk + 0][br] = v.x; Bs[bk + 1][br] = v.y;
                Bs[bk + 2][br] = v.z; Bs[bk + 3][br] = v.w;
            }
        } else {
            #pragma unroll
            for (int i = 0; i < 2; i++) {
                int idx = tid + i * 256;
                int bk = idx >> 5;
                int bn = (idx & 31) * 4;
                const float4 v = *(const float4*)(Bm + (int64_t)(k0 + bk) * ldb + n0 + bn);
                *(float4*)&Bs[bk][bn] = v;
            }
        }
        __syncthreads();

        #pragma unroll
        for (int k = 0; k < BK; k++) {
            float a[8], b[8];
            *(float4*)&a[0] = *(const float4*)&As[k][tm * 8];
            *(float4*)&a[4] = *(const float4*)&As[k][tm * 8 + 4];
            *(float4*)&b[0] = *(const float4*)&Bs[k][tn * 8];
            *(float4*)&b[4] = *(const float4*)&Bs[k][tn * 8 + 4];
            #pragma unroll
            for (int i = 0; i < 8; i++)
                #pragma unroll
                for (int j = 0; j < 8; j++)
                    acc[i][j] += a[i] * b[j];
        }
        __syncthreads();
    }

    float bv[8];
    #pragma unroll
    for (int j = 0; j < 8; j++) {
        int n = n0 + tn * 8 + j;
        float b = 0.0f;
        if (bias1) b += bias1[n];
        if (bias2) b += bias2[n];
        bv[j] = b;
    }
    #pragma unroll
    for (int i = 0; i < 8; i++) {
        int64_t m = m0 + tm * 8 + i;
        float o[8];
        #pragma unroll
        for (int j = 0; j < 8; j++) {
            float v = acc[i][j] + bv[j];
            if (ACT == 1) v = tanhf(v);
            o[j] = v;
        }
        *(float4*)(C + m * ldc + n0 + tn * 8)     = make_float4(o[0], o[1], o[2], o[3]);
        *(float4*)(C + m * ldc + n0 + tn * 8 + 4) = make_float4(o[4], o[5], o[6], o[7]);
    }
}

// ---------------------------------------------------------------------------
// LSTM recurrence chain (one batch per block), shared by producer (ROLE=0,
// layer 0, Ag from global, publishes X1 + pflag per chunk) and consumer
// (ROLE=1, layer 1, Ag from ring after wflag acquire, publishes cflag).
template<int ROLE>
__device__ __forceinline__ void lstm_chain(
    int b, int t,
    const float* __restrict__ Ag,      // ROLE 0 only
    float* __restrict__ ring,          // ROLE 1 only
    const float4* __restrict__ Wpk,
    const float* __restrict__ h0l, const float* __restrict__ c0l,
    float* __restrict__ Xout, int ldx,
    int* __restrict__ pflag, int* __restrict__ wflag, int* __restrict__ cflag,
    float* hsh, float* gsh, float4* Wl)
{
    // --- weights into registers (40 VGPRs)
    float4 wreg[2 * UREG];
    #pragma unroll
    for (int u = 0; u < UREG; u++) {
        wreg[2 * u]     = Wpk[(u * 2 + 0) * 512 + t];
        wreg[2 * u + 1] = Wpk[(u * 2 + 1) * 512 + t];
    }
    // --- weights into LDS (once)
    #pragma unroll
    for (int v = 0; v < ULDS; v++) {
        Wl[(v * 2 + 0) * 512 + t] = Wpk[((UREG + v) * 2 + 0) * 512 + t];
        Wl[(v * 2 + 1) * 512 + t] = Wpk[((UREG + v) * 2 + 1) * 512 + t];
    }
    const float4* __restrict__ Ws = Wpk + (UREG + ULDS) * 2 * 512;

    if (t < HT) hsh[t] = h0l[b * HT + t];
    float c = (t < HT) ? c0l[b * HT + t] : 0.0f;
    __syncthreads();

    const float4* hsh4 = (const float4*)hsh;
    const float* AgB = (ROLE == 0) ? Ag + (int64_t)b * TT * GATES : nullptr;

    for (int st = 0; st < TT; st++) {
        float2 acc;
        if (ROLE == 0) {
            acc = *(const float2*)(AgB + (int64_t)st * GATES + 2 * t);
        } else {
            int ci = st >> 4;
            if ((st & (CCH - 1)) == 0) {
                if (t == 0) {
                    while (__hip_atomic_load(&wflag[b * NCH + ci], __ATOMIC_ACQUIRE,
                                             __HIP_MEMORY_SCOPE_AGENT) == 0)
                        __builtin_amdgcn_s_sleep(2);
                }
                __syncthreads();   // all threads wait for t0's acquire
            }
            float* rs = ring + ((int64_t)(b * RING + (ci % RING)) * CCH + (st & (CCH - 1))) * GATES;
            acc.x = __hip_atomic_load(&rs[2 * t],     __ATOMIC_RELAXED, __HIP_MEMORY_SCOPE_AGENT);
            acc.y = __hip_atomic_load(&rs[2 * t + 1], __ATOMIC_RELAXED, __HIP_MEMORY_SCOPE_AGENT);
        }

        // streamed portion first: longest-latency loads issue earliest
        #pragma unroll 5
        for (int u = 0; u < USTR; u++) {
            float4 wa = Ws[(u * 2 + 0) * 512 + t];
            float4 wb = Ws[(u * 2 + 1) * 512 + t];
            float4 h4 = hsh4[UREG + ULDS + u];
            acc.x += wa.x * h4.x + wa.y * h4.y + wa.z * h4.z + wa.w * h4.w;
            acc.y += wb.x * h4.x + wb.y * h4.y + wb.z * h4.z + wb.w * h4.w;
        }
        #pragma unroll
        for (int v = 0; v < ULDS; v++) {
            float4 h4 = hsh4[UREG + v];
            float4 wa = Wl[(v * 2 + 0) * 512 + t];
            float4 wb = Wl[(v * 2 + 1) * 512 + t];
            acc.x += wa.x * h4.x + wa.y * h4.y + wa.z * h4.z + wa.w * h4.w;
            acc.y += wb.x * h4.x + wb.y * h4.y + wb.z * h4.z + wb.w * h4.w;
        }
        #pragma unroll
        for (int u = 0; u < UREG; u++) {
            float4 h4 = hsh4[u];
            float4 wa = wreg[2 * u], wb = wreg[2 * u + 1];
            acc.x += wa.x * h4.x + wa.y * h4.y + wa.z * h4.z + wa.w * h4.w;
            acc.y += wb.x * h4.x + wb.y * h4.y + wb.z * h4.z + wb.w * h4.w;
        }
        *(float2*)&gsh[2 * t] = acc;
        __syncthreads();                       // gates complete

        if (t < HT) {
            float gi = gsh[t];
            float gf = gsh[HT + t];
            float gg = gsh[2 * HT + t];
            float go = gsh[3 * HT + t];
            c = sigmoidf_(gf) * c + sigmoidf_(gi) * tanhf(gg);
            float h = sigmoidf_(go) * tanhf(c);
            if (ROLE == 0) {
                // publish X1 through the coherence point for the GEMM workers
                __hip_atomic_store(&Xout[((int64_t)b * TT + st) * ldx + t], h,
                                   __ATOMIC_RELAXED, __HIP_MEMORY_SCOPE_AGENT);
            } else {
                Xout[((int64_t)b * TT + st) * ldx + t] = h;
            }
            hsh[t] = h;                        // safe: dots done at barrier above
        }
        __syncthreads();                       // h visible; vm/lgkm drained

        if ((st & (CCH - 1)) == CCH - 1 && t == 0) {
            if (ROLE == 0)
                __hip_atomic_fetch_add(&pflag[b], 1, __ATOMIC_RELEASE, __HIP_MEMORY_SCOPE_AGENT);
            else
                __hip_atomic_store(&cflag[b], (st >> 4) + 1, __ATOMIC_RELEASE, __HIP_MEMORY_SCOPE_AGENT);
        }
    }
}

// Ag1 chunk-GEMM worker: task (b,ci) computes ring slot = X1[b, ci*16..+16) @
// Wih1^T + (bih1+bhh1).  16x1024x256 per task; thread owns 2 output columns.
__device__ __forceinline__ void ag1_worker(
    int w, int t,
    const float* __restrict__ xbuf, const float* __restrict__ WihT,
    const float* __restrict__ bih, const float* __restrict__ bhh,
    float* __restrict__ ring,
    int* __restrict__ pflag, int* __restrict__ wflag, int* __restrict__ cflag,
    float* AshT)   // [256][16] in LDS (aliases Wl)
{
    for (int tau = w; tau < 64 * NCH; tau += 128) {
        int ci = tau >> 6;
        int b  = tau & 63;
        if (t == 0) {
            if (ci >= RING) {   // ring backpressure: slot ci%RING free?
                while (__hip_atomic_load(&cflag[b], __ATOMIC_ACQUIRE,
                                         __HIP_MEMORY_SCOPE_AGENT) < ci - RING + 1)
                    __builtin_amdgcn_s_sleep(2);
            }
            while (__hip_atomic_load(&pflag[b], __ATOMIC_ACQUIRE,
                                     __HIP_MEMORY_SCOPE_AGENT) < ci + 1)
                __builtin_amdgcn_s_sleep(2);
        }
        __syncthreads();

        // stage X1 chunk into LDS, transposed to [k][r]
        #pragma unroll
        for (int i = 0; i < 2; i++) {
            int f  = t * 2 + i;            // 0..1023
            int r  = f >> 6;               // 0..15
            int kq = f & 63;               // 0..63
            float4 v = *(const float4*)(xbuf + ((int64_t)b * TT + ci * CCH + r) * HT + kq * 4);
            AshT[(kq * 4 + 0) * 16 + r] = v.x;
            AshT[(kq * 4 + 1) * 16 + r] = v.y;
            AshT[(kq * 4 + 2) * 16 + r] = v.z;
            AshT[(kq * 4 + 3) * 16 + r] = v.w;
        }
        __syncthreads();

        const int n0 = 2 * t;
        float acc0[16] = {}, acc1[16] = {};
        const float2* Wt2 = (const float2*)WihT;
        #pragma unroll 4
        for (int k = 0; k < HT; k++) {
            float2 wv = Wt2[(int64_t)k * 512 + t];
            float a[16];
            const float4* ar = (const float4*)&AshT[k * 16];
            *(float4*)&a[0]  = ar[0];
            *(float4*)&a[4]  = ar[1];
            *(float4*)&a[8]  = ar[2];
            *(float4*)&a[12] = ar[3];
            #pragma unroll
            for (int r = 0; r < 16; r++) {
                acc0[r] += a[r] * wv.x;
                acc1[r] += a[r] * wv.y;
            }
        }
        float bs0 = bih[GATES + n0]     + bhh[GATES + n0];
        float bs1 = bih[GATES + n0 + 1] + bhh[GATES + n0 + 1];
        float* rs = ring + (int64_t)(b * RING + (ci % RING)) * CCH * GATES;
        #pragma unroll
        for (int r = 0; r < 16; r++) {
            __hip_atomic_store(&rs[r * GATES + n0],     acc0[r] + bs0,
                               __ATOMIC_RELAXED, __HIP_MEMORY_SCOPE_AGENT);
            __hip_atomic_store(&rs[r * GATES + n0 + 1], acc1[r] + bs1,
                               __ATOMIC_RELAXED, __HIP_MEMORY_SCOPE_AGENT);
        }
        __syncthreads();   // all stores drained (vmcnt) before the flag
        if (t == 0)
            __hip_atomic_fetch_add(&wflag[b * NCH + ci], 1, __ATOMIC_RELEASE,
                                   __HIP_MEMORY_SCOPE_AGENT);
    }
}

// Fused 2-layer LSTM pipeline.  grid: 256 blocks x 512 threads, 1 block/CU
// (LDS 149 KB).  Blocks 0-63: layer-0 producers (wait-free, dispatched first);
// 64-127: layer-1 consumers; 128-255: Ag1 GEMM workers.
__global__ __launch_bounds__(512) void lstm_pipe_kernel(
    const float* __restrict__ Ag0, const float4* __restrict__ Wpk,
    const float* __restrict__ WihT,
    const float* __restrict__ bih, const float* __restrict__ bhh,
    const float* __restrict__ h0, const float* __restrict__ c0,
    float* __restrict__ xbuf, float* __restrict__ cat,
    float* __restrict__ ring, int* __restrict__ flags)
{
    __shared__ __align__(16) float4 Wl[ULDS * 2 * 512];   // 144 KB
    __shared__ __align__(16) float  hsh[HT];
    __shared__ __align__(16) float  gsh[GATES];

    int* pflag = flags;          // [64]
    int* cflag = flags + 64;     // [64]
    int* wflag = flags + 128;    // [64*32]

    const int blk = blockIdx.x;
    const int t = threadIdx.x;

    if (blk < 64) {
        lstm_chain<0>(blk, t, Ag0, nullptr, Wpk, h0, c0, xbuf, HT,
                      pflag, wflag, cflag, hsh, gsh, Wl);
    } else if (blk < 128) {
        lstm_chain<1>(blk - 64, t, nullptr, ring, Wpk + 65536,
                      h0 + BB * HT, c0 + BB * HT, cat, 2 * HT,
                      pflag, wflag, cflag, hsh, gsh, Wl);
    } else {
        ag1_worker(blk - 128, t, xbuf, WihT, bih, bhh, ring,
                   pflag, wflag, cflag, (float*)Wl);
    }
}

// ---------------------------------------------------------------------------
__global__ __launch_bounds__(256) void softmax512_kernel(float* __restrict__ S)
{
    int row = blockIdx.x * 4 + (threadIdx.x >> 6);
    int lane = threadIdx.x & 63;
    float* p = S + (int64_t)row * 512 + lane * 8;
    float4 v0 = *(float4*)p;
    float4 v1 = *(float4*)(p + 4);
    float m = fmaxf(fmaxf(fmaxf(v0.x, v0.y), fmaxf(v0.z, v0.w)),
                    fmaxf(fmaxf(v1.x, v1.y), fmaxf(v1.z, v1.w)));
    #pragma unroll
    for (int off = 32; off; off >>= 1) m = fmaxf(m, __shfl_xor(m, off));
    v0.x = __expf(v0.x - m); v0.y = __expf(v0.y - m);
    v0.z = __expf(v0.z - m); v0.w = __expf(v0.w - m);
    v1.x = __expf(v1.x - m); v1.y = __expf(v1.y - m);
    v1.z = __expf(v1.z - m); v1.w = __expf(v1.w - m);
    float s = v0.x + v0.y + v0.z + v0.w + v1.x + v1.y + v1.z + v1.w;
    #pragma unroll
    for (int off = 32; off; off >>= 1) s += __shfl_xor(s, off);
    float inv = 1.0f / s;
    v0.x *= inv; v0.y *= inv; v0.z *= inv; v0.w *= inv;
    v1.x *= inv; v1.y *= inv; v1.z *= inv; v1.w *= inv;
    *(float4*)p = v0;
    *(float4*)(p + 4) = v1;
}

__global__ __launch_bounds__(256) void values_kernel(
    const float* __restrict__ Q, const float* __restrict__ L, float* __restrict__ V)
{
    int row = blockIdx.x * 4 + (threadIdx.x >> 6);
    int lane = threadIdx.x & 63;
    float2 q = *(const float2*)(Q + (int64_t)row * OO + lane * 2);
    float2 l = *(const float2*)(L + (int64_t)row * OO + lane * 2);
    float s = q.x * l.x + q.y * l.y;
    #pragma unroll
    for (int off = 32; off; off >>= 1) s += __shfl_xor(s, off);
    if (lane == 0) V[row] = s;
}

// ---------------------------------------------------------------------------
extern "C" void kernel_launch(void* const* d_in, const int* in_sizes, int n_in,
                              void* d_out, int out_size, void* d_ws, size_t ws_size,
                              hipStream_t stream)
{
    const float* enc      = (const float*)d_in[0];
    const float* h0       = (const float*)d_in[1];
    const float* c0       = (const float*)d_in[2];
    const int*   actions  = (const int*)  d_in[3];
    const float* emb_t    = (const float*)d_in[4];
    const float* Wih      = (const float*)d_in[5];
    const float* Whh      = (const float*)d_in[6];
    const float* bih      = (const float*)d_in[7];
    const float* bhh      = (const float*)d_in[8];
    const float* W_attn   = (const float*)d_in[9];
    const float* b_attn   = (const float*)d_in[10];
    const float* W_concat = (const float*)d_in[11];
    const float* b_concat = (const float*)d_in[12];
    const float* W_out    = (const float*)d_in[13];
    const float* W_critic = (const float*)d_in[14];
    const float* b_critic = (const float*)d_in[15];
    (void)in_sizes; (void)n_in; (void)out_size; (void)ws_size;

    const int M = BB * TT;                 // 32768

    float* out    = (float*)d_out;
    float* dact   = out;
    float* logits = out + M;
    float* values = out + M + (int64_t)M * OO;

    // Workspace arena (floats), 256 MiB total:
    //   gates : 33,554,432   (Ag0; later scores then qv)
    //   xbuf  :  8,388,608   (emb -> X1 -> dec)
    //   cat   : 16,777,216   ([out | ctx] row stride 512)
    //   keysR :  8,388,608   (Wpk+WihT+ring+flags during LSTM; keys after)
    float* ws    = (float*)d_ws;
    float* gates = ws;
    float* xbuf  = ws + 33554432;
    float* cat   = ws + 41943040;
    float* keysR = ws + 58720256;
    float* keys  = keysR;
    float4* Wpk4 = (float4*)keysR;                 // 131072 f4 = 2 MB
    float* WihT  = keysR + 524288;                 // 1 MB
    float* ring  = keysR + 786432;                 // 64*6*16*1024 fl = 24 MB
    int*   flags = (int*)(keysR + 7077888);        // 2176 ints
    float* scores = gates;
    float* qv     = gates;
    float* dec    = xbuf;

    // 1) embedding + decoder_action
    hipLaunchKernelGGL(embed_kernel, dim3(M), dim3(256), 0, stream,
                       actions, emb_t, xbuf, dact);
    // 2) repack Whh / transpose Wih1 / zero flags
    hipLaunchKernelGGL(repack_whh_kernel, dim3(512), dim3(256), 0, stream,
                       Whh, Wpk4);
    hipLaunchKernelGGL(transpose_wih1_kernel, dim3(1024), dim3(256), 0, stream,
                       Wih, WihT);
    hipLaunchKernelGGL(zero_kernel, dim3(9), dim3(256), 0, stream,
                       flags, 64 + 64 + 64 * NCH);
    // 3) layer-0 input GEMM: gates = emb @ Wih0^T + bih0 + bhh0
    hipLaunchKernelGGL((gemm128_kernel<true, 0>), dim3(8, 256, 1), dim3(256), 0, stream,
                       xbuf, Wih, gates, HT, HT, HT, GATES,
                       (int64_t)0, (int64_t)0, (int64_t)0, bih, bhh);
    // 4) fused 2-layer LSTM pipeline: layer0 -> Ag1 workers -> layer1
    hipLaunchKernelGGL(lstm_pipe_kernel, dim3(256), dim3(512), 0, stream,
                       gates, Wpk4, WihT, bih, bhh, h0, c0, xbuf, cat, ring, flags);
    // 5) keys = enc @ W_attn^T + b_attn   (overwrites Wpk/ring region)
    hipLaunchKernelGGL((gemm128_kernel<true, 0>), dim3(2, 256, 1), dim3(256), 0, stream,
                       enc, W_attn, keys, HT, HT, HT, HT,
                       (int64_t)0, (int64_t)0, (int64_t)0, b_attn, (const float*)nullptr);
    // 6) scores[b] = out[b] @ keys[b]^T
    hipLaunchKernelGGL((gemm128_kernel<true, 0>), dim3(4, 4, BB), dim3(256), 0, stream,
                       cat, keys, scores, HT, 2 * HT, HT, TT,
                       (int64_t)TT * 2 * HT, (int64_t)TT * HT, (int64_t)TT * TT,
                       (const float*)nullptr, (const float*)nullptr);
    // 7) softmax
    hipLaunchKernelGGL(softmax512_kernel, dim3(M / 4), dim3(256), 0, stream, scores);
    // 8) ctx[b] = P[b] @ enc[b] -> cat[:,256:]
    hipLaunchKernelGGL((gemm128_kernel<false, 0>), dim3(2, 4, BB), dim3(256), 0, stream,
                       scores, enc, cat + HT, TT, TT, HT, 2 * HT,
                       (int64_t)TT * TT, (int64_t)TT * HT, (int64_t)TT * 2 * HT,
                       (const float*)nullptr, (const float*)nullptr);
    // 9) dec = tanh(cat @ W_concat^T + b_concat)
    hipLaunchKernelGGL((gemm128_kernel<true, 1>), dim3(2, 256, 1), dim3(256), 0, stream,
                       cat, W_concat, dec, 2 * HT, 2 * HT, 2 * HT, HT,
                       (int64_t)0, (int64_t)0, (int64_t)0, b_concat, (const float*)nullptr);
    // 10) logits = dec @ W_out^T
    hipLaunchKernelGGL((gemm128_kernel<true, 0>), dim3(1, 256, 1), dim3(256), 0, stream,
                       dec, W_out, logits, HT, HT, HT, OO,
                       (int64_t)0, (int64_t)0, (int64_t)0,
                       (const float*)nullptr, (const float*)nullptr);
    // 11) qv = logits @ W_critic^T + b_critic
    hipLaunchKernelGGL((gemm128_kernel<true, 0>), dim3(1, 256, 1), dim3(256), 0, stream,
                       logits, W_critic, qv, OO, OO, OO, OO,
                       (int64_t)0, (int64_t)0, (int64_t)0, b_critic, (const float*)nullptr);
    // 12) values
    hipLaunchKernelGGL(values_kernel, dim3(M / 4), dim3(256), 0, stream,
                       qv, logits, values);
}

// Round 7
// 4813.948 us; speedup vs baseline: 5.2608x; 5.2608x over previous
//
#include <hip/hip_runtime.h>
#include <stdint.h>

// Problem constants
#define BB   64
#define TT   512
#define HT   256
#define OO   128
#define GATES 1024   // 4*H

// lstm weight-persistence split, fp16 weights. Unit = 4 consecutive k values;
// per unit per thread: 8 halfs = rows (2t,2t+1) x k[4u..4u+3] = one uint4.
// Budgets validated in R5: 512-thread blocks get 128 VGPRs (more spills),
// LDS <= 160 KB/WG. fp16 doubles what fits per byte.
#define UREG 12                    // units in VGPRs: 48 VGPR/lane
#define ULDS 18                    // units in LDS: 18*512*16 B = 144 KB
#define USTR (64 - UREG - ULDS)    // 34 units streamed from L2 each step (272 KB)

typedef _Float16 half_t;
typedef _Float16 half2_t __attribute__((ext_vector_type(2)));

__device__ __forceinline__ half2_t h2_(unsigned int x) {
    return __builtin_bit_cast(half2_t, x);
}
__device__ __forceinline__ float sigmoidf_(float x) {
    return 1.0f / (1.0f + __expf(-x));
}

// ---------------------------------------------------------------------------
// Embedding gather + decoder_action output
__global__ __launch_bounds__(256) void embed_kernel(
    const int* __restrict__ actions, const float* __restrict__ emb_table,
    float* __restrict__ X, float* __restrict__ dact)
{
    int row = blockIdx.x;
    int t = row & (TT - 1);
    int id = (t == 0) ? 0 : actions[row - 1];
    X[(int64_t)row * HT + threadIdx.x] = emb_table[(int64_t)id * HT + threadIdx.x];
    if (threadIdx.x == 0) dact[row] = (float)actions[row];
}

// ---------------------------------------------------------------------------
// Repack Whh to fp16 in the lstm load layout:
// Wpkh[(l*64 + u)*512 + t] = uint4 of 8 halfs:
//   {W[2t][4u],W[2t][4u+1]} {W[2t][4u+2],W[2t][4u+3]}
//   {W[2t+1][4u],W[2t+1][4u+1]} {W[2t+1][4u+2],W[2t+1][4u+3]}
// grid: 256 blocks x 256 threads (65536 uint4)
__global__ __launch_bounds__(256) void repack_whh_h_kernel(
    const float* __restrict__ Whh, uint4* __restrict__ Wpkh)
{
    int idx = blockIdx.x * 256 + threadIdx.x;   // 0..65535
    int t = idx & 511;
    int u = (idx >> 9) & 63;
    int l = idx >> 15;
    const float* base = Whh + (int64_t)l * (GATES * HT);
    const float4 a = *(const float4*)(base + (int64_t)(2 * t)     * HT + 4 * u);
    const float4 b = *(const float4*)(base + (int64_t)(2 * t + 1) * HT + 4 * u);
    half2_t p0 = {(half_t)a.x, (half_t)a.y};
    half2_t p1 = {(half_t)a.z, (half_t)a.w};
    half2_t p2 = {(half_t)b.x, (half_t)b.y};
    half2_t p3 = {(half_t)b.z, (half_t)b.w};
    uint4 o;
    o.x = __builtin_bit_cast(unsigned int, p0);
    o.y = __builtin_bit_cast(unsigned int, p1);
    o.z = __builtin_bit_cast(unsigned int, p2);
    o.w = __builtin_bit_cast(unsigned int, p3);
    Wpkh[idx] = o;
}

// ---------------------------------------------------------------------------
// Generic fp32 tiled GEMM: C = act( A @ op(B) + bias1 + bias2 )
// BM=BN=128, BK=16, 256 threads, 8x8 per thread. Dims divisible.
template<bool TRANS_B, int ACT>
__global__ __launch_bounds__(256) void gemm128_kernel(
    const float* __restrict__ A, const float* __restrict__ Bm,
    float* __restrict__ C,
    int K, int lda, int ldb, int ldc,
    int64_t sA, int64_t sB, int64_t sC,
    const float* __restrict__ bias1, const float* __restrict__ bias2)
{
    constexpr int BM = 128, BN = 128, BK = 16;
    __shared__ __align__(16) float As[BK][BM + 4];
    __shared__ __align__(16) float Bs[BK][BN + 4];

    const int tid = threadIdx.x;
    const int m0 = blockIdx.y * BM;
    const int n0 = blockIdx.x * BN;
    A  += (int64_t)blockIdx.z * sA;
    Bm += (int64_t)blockIdx.z * sB;
    C  += (int64_t)blockIdx.z * sC;

    const int tm = tid & 15;
    const int tn = tid >> 4;

    float acc[8][8] = {};

    for (int k0 = 0; k0 < K; k0 += BK) {
        #pragma unroll
        for (int i = 0; i < 2; i++) {
            int idx = tid + i * 256;
            int ar = idx >> 2;
            int ak = (idx & 3) * 4;
            const float4 v = *(const float4*)(A + (int64_t)(m0 + ar) * lda + k0 + ak);
            As[ak + 0][ar] = v.x; As[ak + 1][ar] = v.y;
            As[ak + 2][ar] = v.z; As[ak + 3][ar] = v.w;
        }
        if (TRANS_B) {
            #pragma unroll
            for (int i = 0; i < 2; i++) {
                int idx = tid + i * 256;
                int br = idx >> 2;
                int bk = (idx & 3) * 4;
                const float4 v = *(const float4*)(Bm + (int64_t)(n0 + br) * ldb + k0 + bk);
                Bs[bk + 0][br] = v.x; Bs[bk + 1][br] = v.y;
                Bs[bk + 2][br] = v.z; Bs[bk + 3][br] = v.w;
            }
        } else {
            #pragma unroll
            for (int i = 0; i < 2; i++) {
                int idx = tid + i * 256;
                int bk = idx >> 5;
                int bn = (idx & 31) * 4;
                const float4 v = *(const float4*)(Bm + (int64_t)(k0 + bk) * ldb + n0 + bn);
                *(float4*)&Bs[bk][bn] = v;
            }
        }
        __syncthreads();

        #pragma unroll
        for (int k = 0; k < BK; k++) {
            float a[8], b[8];
            *(float4*)&a[0] = *(const float4*)&As[k][tm * 8];
            *(float4*)&a[4] = *(const float4*)&As[k][tm * 8 + 4];
            *(float4*)&b[0] = *(const float4*)&Bs[k][tn * 8];
            *(float4*)&b[4] = *(const float4*)&Bs[k][tn * 8 + 4];
            #pragma unroll
            for (int i = 0; i < 8; i++)
                #pragma unroll
                for (int j = 0; j < 8; j++)
                    acc[i][j] += a[i] * b[j];
        }
        __syncthreads();
    }

    float bv[8];
    #pragma unroll
    for (int j = 0; j < 8; j++) {
        int n = n0 + tn * 8 + j;
        float b = 0.0f;
        if (bias1) b += bias1[n];
        if (bias2) b += bias2[n];
        bv[j] = b;
    }
    #pragma unroll
    for (int i = 0; i < 8; i++) {
        int64_t m = m0 + tm * 8 + i;
        float o[8];
        #pragma unroll
        for (int j = 0; j < 8; j++) {
            float v = acc[i][j] + bv[j];
            if (ACT == 1) v = tanhf(v);
            o[j] = v;
        }
        *(float4*)(C + m * ldc + n0 + tn * 8)     = make_float4(o[0], o[1], o[2], o[3]);
        *(float4*)(C + m * ldc + n0 + tn * 8 + 4) = make_float4(o[4], o[5], o[6], o[7]);
    }
}

// ---------------------------------------------------------------------------
// LSTM recurrence, weight-persistent single-workgroup, fp16 weights + fdot2.
// grid: 64 blocks (one per batch) x 512 threads = 8 waves.
// Thread t owns gate rows (2t, 2t+1). Weight source per unit u (k=4u..4u+3):
//   u < UREG        : VGPRs (loaded once)
//   u < UREG+ULDS   : LDS   (staged once)
//   else            : streamed from L2 every step (272 KB; the limiter)
// h kept as fp16 in LDS; products exact in fp32 via v_dot2_f32_f16.
__global__ __launch_bounds__(512) void lstm_rec_kernel(
    const float* __restrict__ Ag,      // [B*T][1024] = x@Wih^T + bih + bhh
    const uint4* __restrict__ Wpk,     // this layer's packed fp16 weights
    const float* __restrict__ h0l,     // [B][256] this layer
    const float* __restrict__ c0l,
    float* __restrict__ X, int ldx)    // h output (fp32), row b*T+t
{
    const int b = blockIdx.x;
    const int t = threadIdx.x;         // 0..511

    __shared__ __align__(16) uint4  Wlh[ULDS * 512];   // 144 KB
    __shared__ __align__(16) float  gsh[GATES];        // 4 KB
    __shared__ __align__(16) half_t hsh_h[HT];         // 512 B

    // --- weights into registers (48 VGPRs)
    uint4 wreg[UREG];
    #pragma unroll
    for (int u = 0; u < UREG; u++) wreg[u] = Wpk[u * 512 + t];
    // --- weights into LDS (once)
    #pragma unroll
    for (int v = 0; v < ULDS; v++) Wlh[v * 512 + t] = Wpk[(UREG + v) * 512 + t];
    const uint4* __restrict__ Ws = Wpk + (UREG + ULDS) * 512;

    // --- state init
    if (t < HT) hsh_h[t] = (half_t)h0l[b * HT + t];
    float c = (t < HT) ? c0l[b * HT + t] : 0.0f;
    __syncthreads();

    const uint2* hp = (const uint2*)hsh_h;   // hp[ku] = halfs h[4ku..4ku+3]
    const float* AgB = Ag + (int64_t)b * TT * GATES;

    for (int st = 0; st < TT; st++) {
        float2 acc = *(const float2*)(AgB + (int64_t)st * GATES + 2 * t);

        // streamed portion first: longest-latency loads issue earliest
        #pragma unroll 5
        for (int u = 0; u < USTR; u++) {
            uint4 wv = Ws[u * 512 + t];
            uint2 hv = hp[UREG + ULDS + u];
            acc.x = __builtin_amdgcn_fdot2(h2_(wv.x), h2_(hv.x), acc.x, false);
            acc.x = __builtin_amdgcn_fdot2(h2_(wv.y), h2_(hv.y), acc.x, false);
            acc.y = __builtin_amdgcn_fdot2(h2_(wv.z), h2_(hv.x), acc.y, false);
            acc.y = __builtin_amdgcn_fdot2(h2_(wv.w), h2_(hv.y), acc.y, false);
        }
        #pragma unroll
        for (int v = 0; v < ULDS; v++) {
            uint4 wv = Wlh[v * 512 + t];
            uint2 hv = hp[UREG + v];
            acc.x = __builtin_amdgcn_fdot2(h2_(wv.x), h2_(hv.x), acc.x, false);
            acc.x = __builtin_amdgcn_fdot2(h2_(wv.y), h2_(hv.y), acc.x, false);
            acc.y = __builtin_amdgcn_fdot2(h2_(wv.z), h2_(hv.x), acc.y, false);
            acc.y = __builtin_amdgcn_fdot2(h2_(wv.w), h2_(hv.y), acc.y, false);
        }
        #pragma unroll
        for (int u = 0; u < UREG; u++) {
            uint4 wv = wreg[u];
            uint2 hv = hp[u];
            acc.x = __builtin_amdgcn_fdot2(h2_(wv.x), h2_(hv.x), acc.x, false);
            acc.x = __builtin_amdgcn_fdot2(h2_(wv.y), h2_(hv.y), acc.x, false);
            acc.y = __builtin_amdgcn_fdot2(h2_(wv.z), h2_(hv.x), acc.y, false);
            acc.y = __builtin_amdgcn_fdot2(h2_(wv.w), h2_(hv.y), acc.y, false);
        }
        *(float2*)&gsh[2 * t] = acc;
        __syncthreads();                       // gates complete

        if (t < HT) {
            float gi = gsh[t];
            float gf = gsh[HT + t];
            float gg = gsh[2 * HT + t];
            float go = gsh[3 * HT + t];
            c = sigmoidf_(gf) * c + sigmoidf_(gi) * tanhf(gg);
            float h = sigmoidf_(go) * tanhf(c);
            X[((int64_t)b * TT + st) * ldx + t] = h;
            hsh_h[t] = (half_t)h;              // safe: dots done at barrier above
        }
        __syncthreads();                       // h visible for next step
    }
}

// ---------------------------------------------------------------------------
__global__ __launch_bounds__(256) void softmax512_kernel(float* __restrict__ S)
{
    int row = blockIdx.x * 4 + (threadIdx.x >> 6);
    int lane = threadIdx.x & 63;
    float* p = S + (int64_t)row * 512 + lane * 8;
    float4 v0 = *(float4*)p;
    float4 v1 = *(float4*)(p + 4);
    float m = fmaxf(fmaxf(fmaxf(v0.x, v0.y), fmaxf(v0.z, v0.w)),
                    fmaxf(fmaxf(v1.x, v1.y), fmaxf(v1.z, v1.w)));
    #pragma unroll
    for (int off = 32; off; off >>= 1) m = fmaxf(m, __shfl_xor(m, off));
    v0.x = __expf(v0.x - m); v0.y = __expf(v0.y - m);
    v0.z = __expf(v0.z - m); v0.w = __expf(v0.w - m);
    v1.x = __expf(v1.x - m); v1.y = __expf(v1.y - m);
    v1.z = __expf(v1.z - m); v1.w = __expf(v1.w - m);
    float s = v0.x + v0.y + v0.z + v0.w + v1.x + v1.y + v1.z + v1.w;
    #pragma unroll
    for (int off = 32; off; off >>= 1) s += __shfl_xor(s, off);
    float inv = 1.0f / s;
    v0.x *= inv; v0.y *= inv; v0.z *= inv; v0.w *= inv;
    v1.x *= inv; v1.y *= inv; v1.z *= inv; v1.w *= inv;
    *(float4*)p = v0;
    *(float4*)(p + 4) = v1;
}

__global__ __launch_bounds__(256) void values_kernel(
    const float* __restrict__ Q, const float* __restrict__ L, float* __restrict__ V)
{
    int row = blockIdx.x * 4 + (threadIdx.x >> 6);
    int lane = threadIdx.x & 63;
    float2 q = *(const float2*)(Q + (int64_t)row * OO + lane * 2);
    float2 l = *(const float2*)(L + (int64_t)row * OO + lane * 2);
    float s = q.x * l.x + q.y * l.y;
    #pragma unroll
    for (int off = 32; off; off >>= 1) s += __shfl_xor(s, off);
    if (lane == 0) V[row] = s;
}

// ---------------------------------------------------------------------------
extern "C" void kernel_launch(void* const* d_in, const int* in_sizes, int n_in,
                              void* d_out, int out_size, void* d_ws, size_t ws_size,
                              hipStream_t stream)
{
    const float* enc      = (const float*)d_in[0];
    const float* h0       = (const float*)d_in[1];
    const float* c0       = (const float*)d_in[2];
    const int*   actions  = (const int*)  d_in[3];
    const float* emb_t    = (const float*)d_in[4];
    const float* Wih      = (const float*)d_in[5];
    const float* Whh      = (const float*)d_in[6];
    const float* bih      = (const float*)d_in[7];
    const float* bhh      = (const float*)d_in[8];
    const float* W_attn   = (const float*)d_in[9];
    const float* b_attn   = (const float*)d_in[10];
    const float* W_concat = (const float*)d_in[11];
    const float* b_concat = (const float*)d_in[12];
    const float* W_out    = (const float*)d_in[13];
    const float* W_critic = (const float*)d_in[14];
    const float* b_critic = (const float*)d_in[15];
    (void)in_sizes; (void)n_in; (void)out_size; (void)ws_size;

    const int M = BB * TT;                 // 32768

    float* out    = (float*)d_out;
    float* dact   = out;
    float* logits = out + M;
    float* values = out + M + (int64_t)M * OO;

    // Workspace arena (floats), 256 MiB total:
    //   gates : 33,554,432   (Ag0; later scores then qv)
    //   xbuf  :  8,388,608   (emb -> X1 -> dec)
    //   cat   : 16,777,216   ([out | ctx] row stride 512)
    //   keysR :  8,388,608   (Wpkh during LSTM; keys after)
    float* ws    = (float*)d_ws;
    float* gates = ws;
    float* xbuf  = ws + 33554432;
    float* cat   = ws + 41943040;
    float* keysR = ws + 58720256;
    float* keys  = keysR;
    uint4* Wpkh  = (uint4*)keysR;          // 65536 uint4 = 1 MB; dead before keys
    float* scores = gates;
    float* qv     = gates;
    float* dec    = xbuf;

    const int64_t LWP = 32768;             // uint4s per layer in Wpkh

    // 1) embedding + decoder_action
    hipLaunchKernelGGL(embed_kernel, dim3(M), dim3(256), 0, stream,
                       actions, emb_t, xbuf, dact);
    // 2) repack Whh to fp16 register/LDS/stream layout
    hipLaunchKernelGGL(repack_whh_h_kernel, dim3(256), dim3(256), 0, stream,
                       Whh, Wpkh);
    // 3) layer-0 input GEMM: gates = emb @ Wih0^T + bih0 + bhh0
    hipLaunchKernelGGL((gemm128_kernel<true, 0>), dim3(8, 256, 1), dim3(256), 0, stream,
                       xbuf, Wih, gates, HT, HT, HT, GATES,
                       (int64_t)0, (int64_t)0, (int64_t)0, bih, bhh);
    // 4) layer-0 recurrence -> X1 (xbuf, ldx=256)
    hipLaunchKernelGGL(lstm_rec_kernel, dim3(BB), dim3(512), 0, stream,
                       gates, Wpkh, h0, c0, xbuf, HT);
    // 5) layer-1 input GEMM
    hipLaunchKernelGGL((gemm128_kernel<true, 0>), dim3(8, 256, 1), dim3(256), 0, stream,
                       xbuf, Wih + (int64_t)GATES * HT, gates, HT, HT, HT, GATES,
                       (int64_t)0, (int64_t)0, (int64_t)0, bih + GATES, bhh + GATES);
    // 6) layer-1 recurrence -> cat[:, 0:256] (ldx=512)
    hipLaunchKernelGGL(lstm_rec_kernel, dim3(BB), dim3(512), 0, stream,
                       gates, Wpkh + LWP, h0 + BB * HT, c0 + BB * HT, cat, 2 * HT);
    // 7) keys = enc @ W_attn^T + b_attn   (overwrites Wpkh region)
    hipLaunchKernelGGL((gemm128_kernel<true, 0>), dim3(2, 256, 1), dim3(256), 0, stream,
                       enc, W_attn, keys, HT, HT, HT, HT,
                       (int64_t)0, (int64_t)0, (int64_t)0, b_attn, (const float*)nullptr);
    // 8) scores[b] = out[b] @ keys[b]^T
    hipLaunchKernelGGL((gemm128_kernel<true, 0>), dim3(4, 4, BB), dim3(256), 0, stream,
                       cat, keys, scores, HT, 2 * HT, HT, TT,
                       (int64_t)TT * 2 * HT, (int64_t)TT * HT, (int64_t)TT * TT,
                       (const float*)nullptr, (const float*)nullptr);
    // 9) softmax
    hipLaunchKernelGGL(softmax512_kernel, dim3(M / 4), dim3(256), 0, stream, scores);
    // 10) ctx[b] = P[b] @ enc[b] -> cat[:,256:]
    hipLaunchKernelGGL((gemm128_kernel<false, 0>), dim3(2, 4, BB), dim3(256), 0, stream,
                       scores, enc, cat + HT, TT, TT, HT, 2 * HT,
                       (int64_t)TT * TT, (int64_t)TT * HT, (int64_t)TT * 2 * HT,
                       (const float*)nullptr, (const float*)nullptr);
    // 11) dec = tanh(cat @ W_concat^T + b_concat)
    hipLaunchKernelGGL((gemm128_kernel<true, 1>), dim3(2, 256, 1), dim3(256), 0, stream,
                       cat, W_concat, dec, 2 * HT, 2 * HT, 2 * HT, HT,
                       (int64_t)0, (int64_t)0, (int64_t)0, b_concat, (const float*)nullptr);
    // 12) logits = dec @ W_out^T
    hipLaunchKernelGGL((gemm128_kernel<true, 0>), dim3(1, 256, 1), dim3(256), 0, stream,
                       dec, W_out, logits, HT, HT, HT, OO,
                       (int64_t)0, (int64_t)0, (int64_t)0,
                       (const float*)nullptr, (const float*)nullptr);
    // 13) qv = logits @ W_critic^T + b_critic
    hipLaunchKernelGGL((gemm128_kernel<true, 0>), dim3(1, 256, 1), dim3(256), 0, stream,
                       logits, W_critic, qv, OO, OO, OO, OO,
                       (int64_t)0, (int64_t)0, (int64_t)0, b_critic, (const float*)nullptr);
    // 14) values
    hipLaunchKernelGGL(values_kernel, dim3(M / 4), dim3(256), 0, stream,
                       qv, logits, values);
}

// Round 8
// 4538.579 us; speedup vs baseline: 5.5800x; 1.0607x over previous
//
#include <hip/hip_runtime.h>
#include <stdint.h>

// Problem constants
#define BB   64
#define TT   512
#define HT   256
#define OO   128
#define GATES 1024   // 4*H

// lstm weight layout (R8): 512 threads, thread (s=tid>>8, q=tid&255) owns
// gate rows 4q..4q+3 and k in [128s, 128s+128).  Unit = 4 consecutive k.
// Per unit per thread: 2 uint4 (A: rows 4q,4q+1; B: rows 4q+2,4q+3), fp16.
// 32 units/thread. Partial dots (k-halves) summed via LDS gsh2.
// Budgets (R3/R4/R5 lessons): 512-thr blocks get 128 VGPRs, LDS <= 160 KB.
#define UREG 9                     // units in VGPRs: 72 VGPR/lane (147 KB/CU)
#define ULDS 9                     // units in LDS: 9*16 KB = 144 KB
#define USTR (32 - UREG - ULDS)    // 14 units streamed from L2/step (224 KB)

typedef _Float16 half_t;
typedef _Float16 half2_t __attribute__((ext_vector_type(2)));

__device__ __forceinline__ half2_t h2_(unsigned int x) {
    return __builtin_bit_cast(half2_t, x);
}
__device__ __forceinline__ float sigmoidf_(float x) {
    return 1.0f / (1.0f + __expf(-x));
}

// ---------------------------------------------------------------------------
// Embedding gather + decoder_action output
__global__ __launch_bounds__(256) void embed_kernel(
    const int* __restrict__ actions, const float* __restrict__ emb_table,
    float* __restrict__ X, float* __restrict__ dact)
{
    int row = blockIdx.x;
    int t = row & (TT - 1);
    int id = (t == 0) ? 0 : actions[row - 1];
    X[(int64_t)row * HT + threadIdx.x] = emb_table[(int64_t)id * HT + threadIdx.x];
    if (threadIdx.x == 0) dact[row] = (float)actions[row];
}

// ---------------------------------------------------------------------------
// Repack Whh to fp16, R8 layout:
// Wpkh[l*32768 + (u*2+ab)*512 + tid], tid=s*256+q, rows r0=4q+2ab, r0+1,
// k-base = 128s+4u.  uint4 halfs: {W[r0][k],W[r0][k+1]} {W[r0][k+2],W[r0][k+3]}
//                                 {W[r1][k],W[r1][k+1]} {W[r1][k+2],W[r1][k+3]}
// grid: 256 blocks x 256 threads (65536 uint4)
__global__ __launch_bounds__(256) void repack_whh_h_kernel(
    const float* __restrict__ Whh, uint4* __restrict__ Wpkh)
{
    int idx = blockIdx.x * 256 + threadIdx.x;   // 0..65535
    int tid = idx & 511;
    int ab  = (idx >> 9) & 1;
    int u   = (idx >> 10) & 31;
    int l   = idx >> 15;
    int s = tid >> 8, q = tid & 255;
    int r0 = 4 * q + 2 * ab;
    int k  = 128 * s + 4 * u;
    const float* base = Whh + (int64_t)l * (GATES * HT);
    const float4 a = *(const float4*)(base + (int64_t)r0 * HT + k);
    const float4 b = *(const float4*)(base + (int64_t)(r0 + 1) * HT + k);
    half2_t p0 = {(half_t)a.x, (half_t)a.y};
    half2_t p1 = {(half_t)a.z, (half_t)a.w};
    half2_t p2 = {(half_t)b.x, (half_t)b.y};
    half2_t p3 = {(half_t)b.z, (half_t)b.w};
    uint4 o;
    o.x = __builtin_bit_cast(unsigned int, p0);
    o.y = __builtin_bit_cast(unsigned int, p1);
    o.z = __builtin_bit_cast(unsigned int, p2);
    o.w = __builtin_bit_cast(unsigned int, p3);
    Wpkh[idx] = o;
}

// ---------------------------------------------------------------------------
// Generic fp32 tiled GEMM: C = act( A @ op(B) + bias1 + bias2 )
// BM=BN=128, BK=16, 256 threads, 8x8 per thread. Dims divisible.
template<bool TRANS_B, int ACT>
__global__ __launch_bounds__(256) void gemm128_kernel(
    const float* __restrict__ A, const float* __restrict__ Bm,
    float* __restrict__ C,
    int K, int lda, int ldb, int ldc,
    int64_t sA, int64_t sB, int64_t sC,
    const float* __restrict__ bias1, const float* __restrict__ bias2)
{
    constexpr int BM = 128, BN = 128, BK = 16;
    __shared__ __align__(16) float As[BK][BM + 4];
    __shared__ __align__(16) float Bs[BK][BN + 4];

    const int tid = threadIdx.x;
    const int m0 = blockIdx.y * BM;
    const int n0 = blockIdx.x * BN;
    A  += (int64_t)blockIdx.z * sA;
    Bm += (int64_t)blockIdx.z * sB;
    C  += (int64_t)blockIdx.z * sC;

    const int tm = tid & 15;
    const int tn = tid >> 4;

    float acc[8][8] = {};

    for (int k0 = 0; k0 < K; k0 += BK) {
        #pragma unroll
        for (int i = 0; i < 2; i++) {
            int idx = tid + i * 256;
            int ar = idx >> 2;
            int ak = (idx & 3) * 4;
            const float4 v = *(const float4*)(A + (int64_t)(m0 + ar) * lda + k0 + ak);
            As[ak + 0][ar] = v.x; As[ak + 1][ar] = v.y;
            As[ak + 2][ar] = v.z; As[ak + 3][ar] = v.w;
        }
        if (TRANS_B) {
            #pragma unroll
            for (int i = 0; i < 2; i++) {
                int idx = tid + i * 256;
                int br = idx >> 2;
                int bk = (idx & 3) * 4;
                const float4 v = *(const float4*)(Bm + (int64_t)(n0 + br) * ldb + k0 + bk);
                Bs[bk + 0][br] = v.x; Bs[bk + 1][br] = v.y;
                Bs[bk + 2][br] = v.z; Bs[bk + 3][br] = v.w;
            }
        } else {
            #pragma unroll
            for (int i = 0; i < 2; i++) {
                int idx = tid + i * 256;
                int bk = idx >> 5;
                int bn = (idx & 31) * 4;
                const float4 v = *(const float4*)(Bm + (int64_t)(k0 + bk) * ldb + n0 + bn);
                *(float4*)&Bs[bk][bn] = v;
            }
        }
        __syncthreads();

        #pragma unroll
        for (int k = 0; k < BK; k++) {
            float a[8], b[8];
            *(float4*)&a[0] = *(const float4*)&As[k][tm * 8];
            *(float4*)&a[4] = *(const float4*)&As[k][tm * 8 + 4];
            *(float4*)&b[0] = *(const float4*)&Bs[k][tn * 8];
            *(float4*)&b[4] = *(const float4*)&Bs[k][tn * 8 + 4];
            #pragma unroll
            for (int i = 0; i < 8; i++)
                #pragma unroll
                for (int j = 0; j < 8; j++)
                    acc[i][j] += a[i] * b[j];
        }
        __syncthreads();
    }

    float bv[8];
    #pragma unroll
    for (int j = 0; j < 8; j++) {
        int n = n0 + tn * 8 + j;
        float b = 0.0f;
        if (bias1) b += bias1[n];
        if (bias2) b += bias2[n];
        bv[j] = b;
    }
    #pragma unroll
    for (int i = 0; i < 8; i++) {
        int64_t m = m0 + tm * 8 + i;
        float o[8];
        #pragma unroll
        for (int j = 0; j < 8; j++) {
            float v = acc[i][j] + bv[j];
            if (ACT == 1) v = tanhf(v);
            o[j] = v;
        }
        *(float4*)(C + m * ldc + n0 + tn * 8)     = make_float4(o[0], o[1], o[2], o[3]);
        *(float4*)(C + m * ldc + n0 + tn * 8 + 4) = make_float4(o[4], o[5], o[6], o[7]);
    }
}

// ---------------------------------------------------------------------------
// LSTM recurrence, weight-persistent, fp16 fdot2, 4-rows/thread k-split.
// grid: 64 blocks (one per batch) x 512 threads = 8 waves.
// Thread (s,q): rows 4q..4q+3, k in [128s,128s+128).  Per unit (4 k):
//   u < UREG        : VGPRs (loaded once)
//   u < UREG+ULDS   : LDS   (staged once)
//   else            : streamed from L2 every step (224 KB; co-limiter)
// h is fp16 in LDS, read b64 per unit (wave-uniform broadcast), each h value
// feeds 4 rows (halves h-read instrs vs 2-row layout).  Partial k-half dots
// combined via gsh2.  Ag added after the dots (latency hidden under them).
__global__ __launch_bounds__(512) void lstm_rec_kernel(
    const float* __restrict__ Ag,      // [B*T][1024] = x@Wih^T + bih + bhh
    const uint4* __restrict__ Wpk,     // this layer's packed fp16 weights
    const float* __restrict__ h0l,     // [B][256] this layer
    const float* __restrict__ c0l,
    float* __restrict__ X, int ldx)    // h output (fp32), row b*T+t
{
    const int b = blockIdx.x;
    const int tid = threadIdx.x;       // 0..511
    const int s = tid >> 8;            // k-half
    const int q = tid & 255;           // row-quad

    __shared__ __align__(16) uint4  Wlh[ULDS * 2 * 512];   // 144 KB
    __shared__ __align__(16) float  gsh2[2 * GATES];       // 8 KB
    __shared__ __align__(16) half_t hsh_h[HT];             // 512 B

    // --- weights into registers (72 VGPRs)
    uint4 wreg[2 * UREG];
    #pragma unroll
    for (int u = 0; u < UREG; u++) {
        wreg[2 * u]     = Wpk[(u * 2 + 0) * 512 + tid];
        wreg[2 * u + 1] = Wpk[(u * 2 + 1) * 512 + tid];
    }
    // --- weights into LDS (once)
    #pragma unroll
    for (int v = 0; v < ULDS; v++) {
        Wlh[(v * 2 + 0) * 512 + tid] = Wpk[((UREG + v) * 2 + 0) * 512 + tid];
        Wlh[(v * 2 + 1) * 512 + tid] = Wpk[((UREG + v) * 2 + 1) * 512 + tid];
    }
    const uint4* __restrict__ Ws = Wpk + (UREG + ULDS) * 2 * 512;

    // --- state init
    if (tid < HT) hsh_h[tid] = (half_t)h0l[b * HT + tid];
    float c = (tid < HT) ? c0l[b * HT + tid] : 0.0f;
    __syncthreads();

    const uint2* hp = (const uint2*)hsh_h;   // hp[32s+u] = halfs h[128s+4u ..+3]
    const int hbase = 32 * s;
    const float* AgB = Ag + (int64_t)b * TT * GATES;

    for (int st = 0; st < TT; st++) {
        // Ag: issued first, consumed last (latency hides under the dots)
        float4 aval = make_float4(0.f, 0.f, 0.f, 0.f);
        if (s == 0) aval = *(const float4*)(AgB + (int64_t)st * GATES + 4 * q);

        float a0 = 0.f, a1 = 0.f, a2 = 0.f, a3 = 0.f;

        // streamed portion first: longest-latency loads issue earliest
        #pragma unroll 3
        for (int u = 0; u < USTR; u++) {
            uint4 wa = Ws[(u * 2 + 0) * 512 + tid];
            uint4 wb = Ws[(u * 2 + 1) * 512 + tid];
            uint2 hv = hp[hbase + UREG + ULDS + u];
            a0 = __builtin_amdgcn_fdot2(h2_(wa.x), h2_(hv.x), a0, false);
            a0 = __builtin_amdgcn_fdot2(h2_(wa.y), h2_(hv.y), a0, false);
            a1 = __builtin_amdgcn_fdot2(h2_(wa.z), h2_(hv.x), a1, false);
            a1 = __builtin_amdgcn_fdot2(h2_(wa.w), h2_(hv.y), a1, false);
            a2 = __builtin_amdgcn_fdot2(h2_(wb.x), h2_(hv.x), a2, false);
            a2 = __builtin_amdgcn_fdot2(h2_(wb.y), h2_(hv.y), a2, false);
            a3 = __builtin_amdgcn_fdot2(h2_(wb.z), h2_(hv.x), a3, false);
            a3 = __builtin_amdgcn_fdot2(h2_(wb.w), h2_(hv.y), a3, false);
        }
        #pragma unroll
        for (int v = 0; v < ULDS; v++) {
            uint4 wa = Wlh[(v * 2 + 0) * 512 + tid];
            uint4 wb = Wlh[(v * 2 + 1) * 512 + tid];
            uint2 hv = hp[hbase + UREG + v];
            a0 = __builtin_amdgcn_fdot2(h2_(wa.x), h2_(hv.x), a0, false);
            a0 = __builtin_amdgcn_fdot2(h2_(wa.y), h2_(hv.y), a0, false);
            a1 = __builtin_amdgcn_fdot2(h2_(wa.z), h2_(hv.x), a1, false);
            a1 = __builtin_amdgcn_fdot2(h2_(wa.w), h2_(hv.y), a1, false);
            a2 = __builtin_amdgcn_fdot2(h2_(wb.x), h2_(hv.x), a2, false);
            a2 = __builtin_amdgcn_fdot2(h2_(wb.y), h2_(hv.y), a2, false);
            a3 = __builtin_amdgcn_fdot2(h2_(wb.z), h2_(hv.x), a3, false);
            a3 = __builtin_amdgcn_fdot2(h2_(wb.w), h2_(hv.y), a3, false);
        }
        #pragma unroll
        for (int u = 0; u < UREG; u++) {
            uint4 wa = wreg[2 * u];
            uint4 wb = wreg[2 * u + 1];
            uint2 hv = hp[hbase + u];
            a0 = __builtin_amdgcn_fdot2(h2_(wa.x), h2_(hv.x), a0, false);
            a0 = __builtin_amdgcn_fdot2(h2_(wa.y), h2_(hv.y), a0, false);
            a1 = __builtin_amdgcn_fdot2(h2_(wa.z), h2_(hv.x), a1, false);
            a1 = __builtin_amdgcn_fdot2(h2_(wa.w), h2_(hv.y), a1, false);
            a2 = __builtin_amdgcn_fdot2(h2_(wb.x), h2_(hv.x), a2, false);
            a2 = __builtin_amdgcn_fdot2(h2_(wb.y), h2_(hv.y), a2, false);
            a3 = __builtin_amdgcn_fdot2(h2_(wb.z), h2_(hv.x), a3, false);
            a3 = __builtin_amdgcn_fdot2(h2_(wb.w), h2_(hv.y), a3, false);
        }
        a0 += aval.x; a1 += aval.y; a2 += aval.z; a3 += aval.w;
        *(float4*)&gsh2[s * GATES + 4 * q] = make_float4(a0, a1, a2, a3);
        __syncthreads();                       // partial gates complete

        if (tid < HT) {
            float gi = gsh2[tid]             + gsh2[GATES + tid];
            float gf = gsh2[HT + tid]        + gsh2[GATES + HT + tid];
            float gg = gsh2[2 * HT + tid]    + gsh2[GATES + 2 * HT + tid];
            float go = gsh2[3 * HT + tid]    + gsh2[GATES + 3 * HT + tid];
            c = sigmoidf_(gf) * c + sigmoidf_(gi) * tanhf(gg);
            float h = sigmoidf_(go) * tanhf(c);
            X[((int64_t)b * TT + st) * ldx + tid] = h;
            hsh_h[tid] = (half_t)h;            // safe: dots done at barrier above
        }
        __syncthreads();                       // h visible for next step
    }
}

// ---------------------------------------------------------------------------
__global__ __launch_bounds__(256) void softmax512_kernel(float* __restrict__ S)
{
    int row = blockIdx.x * 4 + (threadIdx.x >> 6);
    int lane = threadIdx.x & 63;
    float* p = S + (int64_t)row * 512 + lane * 8;
    float4 v0 = *(float4*)p;
    float4 v1 = *(float4*)(p + 4);
    float m = fmaxf(fmaxf(fmaxf(v0.x, v0.y), fmaxf(v0.z, v0.w)),
                    fmaxf(fmaxf(v1.x, v1.y), fmaxf(v1.z, v1.w)));
    #pragma unroll
    for (int off = 32; off; off >>= 1) m = fmaxf(m, __shfl_xor(m, off));
    v0.x = __expf(v0.x - m); v0.y = __expf(v0.y - m);
    v0.z = __expf(v0.z - m); v0.w = __expf(v0.w - m);
    v1.x = __expf(v1.x - m); v1.y = __expf(v1.y - m);
    v1.z = __expf(v1.z - m); v1.w = __expf(v1.w - m);
    float s = v0.x + v0.y + v0.z + v0.w + v1.x + v1.y + v1.z + v1.w;
    #pragma unroll
    for (int off = 32; off; off >>= 1) s += __shfl_xor(s, off);
    float inv = 1.0f / s;
    v0.x *= inv; v0.y *= inv; v0.z *= inv; v0.w *= inv;
    v1.x *= inv; v1.y *= inv; v1.z *= inv; v1.w *= inv;
    *(float4*)p = v0;
    *(float4*)(p + 4) = v1;
}

__global__ __launch_bounds__(256) void values_kernel(
    const float* __restrict__ Q, const float* __restrict__ L, float* __restrict__ V)
{
    int row = blockIdx.x * 4 + (threadIdx.x >> 6);
    int lane = threadIdx.x & 63;
    float2 q = *(const float2*)(Q + (int64_t)row * OO + lane * 2);
    float2 l = *(const float2*)(L + (int64_t)row * OO + lane * 2);
    float s = q.x * l.x + q.y * l.y;
    #pragma unroll
    for (int off = 32; off; off >>= 1) s += __shfl_xor(s, off);
    if (lane == 0) V[row] = s;
}

// ---------------------------------------------------------------------------
extern "C" void kernel_launch(void* const* d_in, const int* in_sizes, int n_in,
                              void* d_out, int out_size, void* d_ws, size_t ws_size,
                              hipStream_t stream)
{
    const float* enc      = (const float*)d_in[0];
    const float* h0       = (const float*)d_in[1];
    const float* c0       = (const float*)d_in[2];
    const int*   actions  = (const int*)  d_in[3];
    const float* emb_t    = (const float*)d_in[4];
    const float* Wih      = (const float*)d_in[5];
    const float* Whh      = (const float*)d_in[6];
    const float* bih      = (const float*)d_in[7];
    const float* bhh      = (const float*)d_in[8];
    const float* W_attn   = (const float*)d_in[9];
    const float* b_attn   = (const float*)d_in[10];
    const float* W_concat = (const float*)d_in[11];
    const float* b_concat = (const float*)d_in[12];
    const float* W_out    = (const float*)d_in[13];
    const float* W_critic = (const float*)d_in[14];
    const float* b_critic = (const float*)d_in[15];
    (void)in_sizes; (void)n_in; (void)out_size; (void)ws_size;

    const int M = BB * TT;                 // 32768

    float* out    = (float*)d_out;
    float* dact   = out;
    float* logits = out + M;
    float* values = out + M + (int64_t)M * OO;

    // Workspace arena (floats), 256 MiB total:
    //   gates : 33,554,432   (Ag0; later scores then qv)
    //   xbuf  :  8,388,608   (emb -> X1 -> dec)
    //   cat   : 16,777,216   ([out | ctx] row stride 512)
    //   keysR :  8,388,608   (Wpkh during LSTM; keys after)
    float* ws    = (float*)d_ws;
    float* gates = ws;
    float* xbuf  = ws + 33554432;
    float* cat   = ws + 41943040;
    float* keysR = ws + 58720256;
    float* keys  = keysR;
    uint4* Wpkh  = (uint4*)keysR;          // 65536 uint4 = 1 MB; dead before keys
    float* scores = gates;
    float* qv     = gates;
    float* dec    = xbuf;

    const int64_t LWP = 32768;             // uint4s per layer in Wpkh

    // 1) embedding + decoder_action
    hipLaunchKernelGGL(embed_kernel, dim3(M), dim3(256), 0, stream,
                       actions, emb_t, xbuf, dact);
    // 2) repack Whh to fp16 register/LDS/stream layout
    hipLaunchKernelGGL(repack_whh_h_kernel, dim3(256), dim3(256), 0, stream,
                       Whh, Wpkh);
    // 3) layer-0 input GEMM: gates = emb @ Wih0^T + bih0 + bhh0
    hipLaunchKernelGGL((gemm128_kernel<true, 0>), dim3(8, 256, 1), dim3(256), 0, stream,
                       xbuf, Wih, gates, HT, HT, HT, GATES,
                       (int64_t)0, (int64_t)0, (int64_t)0, bih, bhh);
    // 4) layer-0 recurrence -> X1 (xbuf, ldx=256)
    hipLaunchKernelGGL(lstm_rec_kernel, dim3(BB), dim3(512), 0, stream,
                       gates, Wpkh, h0, c0, xbuf, HT);
    // 5) layer-1 input GEMM
    hipLaunchKernelGGL((gemm128_kernel<true, 0>), dim3(8, 256, 1), dim3(256), 0, stream,
                       xbuf, Wih + (int64_t)GATES * HT, gates, HT, HT, HT, GATES,
                       (int64_t)0, (int64_t)0, (int64_t)0, bih + GATES, bhh + GATES);
    // 6) layer-1 recurrence -> cat[:, 0:256] (ldx=512)
    hipLaunchKernelGGL(lstm_rec_kernel, dim3(BB), dim3(512), 0, stream,
                       gates, Wpkh + LWP, h0 + BB * HT, c0 + BB * HT, cat, 2 * HT);
    // 7) keys = enc @ W_attn^T + b_attn   (overwrites Wpkh region)
    hipLaunchKernelGGL((gemm128_kernel<true, 0>), dim3(2, 256, 1), dim3(256), 0, stream,
                       enc, W_attn, keys, HT, HT, HT, HT,
                       (int64_t)0, (int64_t)0, (int64_t)0, b_attn, (const float*)nullptr);
    // 8) scores[b] = out[b] @ keys[b]^T
    hipLaunchKernelGGL((gemm128_kernel<true, 0>), dim3(4, 4, BB), dim3(256), 0, stream,
                       cat, keys, scores, HT, 2 * HT, HT, TT,
                       (int64_t)TT * 2 * HT, (int64_t)TT * HT, (int64_t)TT * TT,
                       (const float*)nullptr, (const float*)nullptr);
    // 9) softmax
    hipLaunchKernelGGL(softmax512_kernel, dim3(M / 4), dim3(256), 0, stream, scores);
    // 10) ctx[b] = P[b] @ enc[b] -> cat[:,256:]
    hipLaunchKernelGGL((gemm128_kernel<false, 0>), dim3(2, 4, BB), dim3(256), 0, stream,
                       scores, enc, cat + HT, TT, TT, HT, 2 * HT,
                       (int64_t)TT * TT, (int64_t)TT * HT, (int64_t)TT * 2 * HT,
                       (const float*)nullptr, (const float*)nullptr);
    // 11) dec = tanh(cat @ W_concat^T + b_concat)
    hipLaunchKernelGGL((gemm128_kernel<true, 1>), dim3(2, 256, 1), dim3(256), 0, stream,
                       cat, W_concat, dec, 2 * HT, 2 * HT, 2 * HT, HT,
                       (int64_t)0, (int64_t)0, (int64_t)0, b_concat, (const float*)nullptr);
    // 12) logits = dec @ W_out^T
    hipLaunchKernelGGL((gemm128_kernel<true, 0>), dim3(1, 256, 1), dim3(256), 0, stream,
                       dec, W_out, logits, HT, HT, HT, OO,
                       (int64_t)0, (int64_t)0, (int64_t)0,
                       (const float*)nullptr, (const float*)nullptr);
    // 13) qv = logits @ W_critic^T + b_critic
    hipLaunchKernelGGL((gemm128_kernel<true, 0>), dim3(1, 256, 1), dim3(256), 0, stream,
                       logits, W_critic, qv, OO, OO, OO, OO,
                       (int64_t)0, (int64_t)0, (int64_t)0, b_critic, (const float*)nullptr);
    // 14) values
    hipLaunchKernelGGL(values_kernel, dim3(M / 4), dim3(256), 0, stream,
                       qv, logits, values);
}

// Round 9
// 3551.810 us; speedup vs baseline: 7.1302x; 1.2778x over previous
//
#include <hip/hip_runtime.h>
#include <stdint.h>

// Problem constants
#define BB   64
#define TT   512
#define HT   256
#define OO   128
#define GATES 1024   // 4*H

// lstm weight layout (R8/R9): 512 threads, thread (s=tid>>8, q=tid&255) owns
// gate rows 4q..4q+3 and k in [128s, 128s+128).  Unit = 4 consecutive k;
// processed in PAIRS (8 k) sharing one b128 h broadcast.
// Per unit per thread: 2 uint4 fp16 (rows 4q,4q+1 | 4q+2,4q+3).
// Budgets (R3/R4/R5): 512-thr blocks get 128 VGPRs, LDS <= 160 KB.
#define PREG 6                     // pairs in VGPRs: 12 units = 96 VGPR/lane
#define PLDS 4                     // pairs in LDS: 8 units = 128 KB
#define PSTR 6                     // pairs streamed from L2/step: 192 KB
#define UREG (2*PREG)
#define ULDS (2*PLDS)

typedef _Float16 half_t;
typedef _Float16 half2_t __attribute__((ext_vector_type(2)));

__device__ __forceinline__ half2_t h2_(unsigned int x) {
    return __builtin_bit_cast(half2_t, x);
}
// lgkm-only workgroup barrier: orders LDS ops without draining vmcnt (the
// default __syncthreads lowers to s_waitcnt vmcnt(0) lgkmcnt(0) + s_barrier,
// which stalls every step on the X global store and kills load overlap).
// 0xC07F = vmcnt 63 (no wait), expcnt 7 (no wait), lgkmcnt 0.
#define WG_BARRIER() do { __builtin_amdgcn_s_waitcnt(0xC07F); \
                          __builtin_amdgcn_s_barrier(); } while (0)

__device__ __forceinline__ float fast_sig(float x) {
    return __builtin_amdgcn_rcpf(1.0f + __expf(-x));
}
__device__ __forceinline__ float fast_tanh(float x) {
    float t = __expf(2.0f * x);
    return 1.0f - 2.0f * __builtin_amdgcn_rcpf(t + 1.0f);
}
__device__ __forceinline__ float sigmoidf_(float x) {
    return 1.0f / (1.0f + __expf(-x));
}

// ---------------------------------------------------------------------------
// Embedding gather + decoder_action output
__global__ __launch_bounds__(256) void embed_kernel(
    const int* __restrict__ actions, const float* __restrict__ emb_table,
    float* __restrict__ X, float* __restrict__ dact)
{
    int row = blockIdx.x;
    int t = row & (TT - 1);
    int id = (t == 0) ? 0 : actions[row - 1];
    X[(int64_t)row * HT + threadIdx.x] = emb_table[(int64_t)id * HT + threadIdx.x];
    if (threadIdx.x == 0) dact[row] = (float)actions[row];
}

// ---------------------------------------------------------------------------
// Repack Whh to fp16 (R8 layout, unit-indexed):
// Wpkh[l*32768 + (u*2+ab)*512 + tid], tid=s*256+q, rows r0=4q+2ab, r0+1,
// k-base = 128s+4u.
__global__ __launch_bounds__(256) void repack_whh_h_kernel(
    const float* __restrict__ Whh, uint4* __restrict__ Wpkh)
{
    int idx = blockIdx.x * 256 + threadIdx.x;   // 0..65535
    int tid = idx & 511;
    int ab  = (idx >> 9) & 1;
    int u   = (idx >> 10) & 31;
    int l   = idx >> 15;
    int s = tid >> 8, q = tid & 255;
    int r0 = 4 * q + 2 * ab;
    int k  = 128 * s + 4 * u;
    const float* base = Whh + (int64_t)l * (GATES * HT);
    const float4 a = *(const float4*)(base + (int64_t)r0 * HT + k);
    const float4 b = *(const float4*)(base + (int64_t)(r0 + 1) * HT + k);
    half2_t p0 = {(half_t)a.x, (half_t)a.y};
    half2_t p1 = {(half_t)a.z, (half_t)a.w};
    half2_t p2 = {(half_t)b.x, (half_t)b.y};
    half2_t p3 = {(half_t)b.z, (half_t)b.w};
    uint4 o;
    o.x = __builtin_bit_cast(unsigned int, p0);
    o.y = __builtin_bit_cast(unsigned int, p1);
    o.z = __builtin_bit_cast(unsigned int, p2);
    o.w = __builtin_bit_cast(unsigned int, p3);
    Wpkh[idx] = o;
}

// ---------------------------------------------------------------------------
// Generic fp32 tiled GEMM: C = act( A @ op(B) + bias1 + bias2 )
// BM=BN=128, BK=16, 256 threads, 8x8 per thread. Dims divisible.
template<bool TRANS_B, int ACT>
__global__ __launch_bounds__(256) void gemm128_kernel(
    const float* __restrict__ A, const float* __restrict__ Bm,
    float* __restrict__ C,
    int K, int lda, int ldb, int ldc,
    int64_t sA, int64_t sB, int64_t sC,
    const float* __restrict__ bias1, const float* __restrict__ bias2)
{
    constexpr int BM = 128, BN = 128, BK = 16;
    __shared__ __align__(16) float As[BK][BM + 4];
    __shared__ __align__(16) float Bs[BK][BN + 4];

    const int tid = threadIdx.x;
    const int m0 = blockIdx.y * BM;
    const int n0 = blockIdx.x * BN;
    A  += (int64_t)blockIdx.z * sA;
    Bm += (int64_t)blockIdx.z * sB;
    C  += (int64_t)blockIdx.z * sC;

    const int tm = tid & 15;
    const int tn = tid >> 4;

    float acc[8][8] = {};

    for (int k0 = 0; k0 < K; k0 += BK) {
        #pragma unroll
        for (int i = 0; i < 2; i++) {
            int idx = tid + i * 256;
            int ar = idx >> 2;
            int ak = (idx & 3) * 4;
            const float4 v = *(const float4*)(A + (int64_t)(m0 + ar) * lda + k0 + ak);
            As[ak + 0][ar] = v.x; As[ak + 1][ar] = v.y;
            As[ak + 2][ar] = v.z; As[ak + 3][ar] = v.w;
        }
        if (TRANS_B) {
            #pragma unroll
            for (int i = 0; i < 2; i++) {
                int idx = tid + i * 256;
                int br = idx >> 2;
                int bk = (idx & 3) * 4;
                const float4 v = *(const float4*)(Bm + (int64_t)(n0 + br) * ldb + k0 + bk);
                Bs[bk + 0][br] = v.x; Bs[bk + 1][br] = v.y;
                Bs[bk + 2][br] = v.z; Bs[bk + 3][br] = v.w;
            }
        } else {
            #pragma unroll
            for (int i = 0; i < 2; i++) {
                int idx = tid + i * 256;
                int bk = idx >> 5;
                int bn = (idx & 31) * 4;
                const float4 v = *(const float4*)(Bm + (int64_t)(k0 + bk) * ldb + n0 + bn);
                *(float4*)&Bs[bk][bn] = v;
            }
        }
        __syncthreads();

        #pragma unroll
        for (int k = 0; k < BK; k++) {
            float a[8], b[8];
            *(float4*)&a[0] = *(const float4*)&As[k][tm * 8];
            *(float4*)&a[4] = *(const float4*)&As[k][tm * 8 + 4];
            *(float4*)&b[0] = *(const float4*)&Bs[k][tn * 8];
            *(float4*)&b[4] = *(const float4*)&Bs[k][tn * 8 + 4];
            #pragma unroll
            for (int i = 0; i < 8; i++)
                #pragma unroll
                for (int j = 0; j < 8; j++)
                    acc[i][j] += a[i] * b[j];
        }
        __syncthreads();
    }

    float bv[8];
    #pragma unroll
    for (int j = 0; j < 8; j++) {
        int n = n0 + tn * 8 + j;
        float b = 0.0f;
        if (bias1) b += bias1[n];
        if (bias2) b += bias2[n];
        bv[j] = b;
    }
    #pragma unroll
    for (int i = 0; i < 8; i++) {
        int64_t m = m0 + tm * 8 + i;
        float o[8];
        #pragma unroll
        for (int j = 0; j < 8; j++) {
            float v = acc[i][j] + bv[j];
            if (ACT == 1) v = tanhf(v);
            o[j] = v;
        }
        *(float4*)(C + m * ldc + n0 + tn * 8)     = make_float4(o[0], o[1], o[2], o[3]);
        *(float4*)(C + m * ldc + n0 + tn * 8 + 4) = make_float4(o[4], o[5], o[6], o[7]);
    }
}

// ---------------------------------------------------------------------------
// Macro: one unit-pair of fdot2s given 4 weight uint4 and one h uint4.
#define PAIR_DOT(wa0, wb0, wa1, wb1, h4)                                  \
    do {                                                                   \
        a0 = __builtin_amdgcn_fdot2(h2_((wa0).x), h2_((h4).x), a0, false); \
        a0 = __builtin_amdgcn_fdot2(h2_((wa0).y), h2_((h4).y), a0, false); \
        a1 = __builtin_amdgcn_fdot2(h2_((wa0).z), h2_((h4).x), a1, false); \
        a1 = __builtin_amdgcn_fdot2(h2_((wa0).w), h2_((h4).y), a1, false); \
        a2 = __builtin_amdgcn_fdot2(h2_((wb0).x), h2_((h4).x), a2, false); \
        a2 = __builtin_amdgcn_fdot2(h2_((wb0).y), h2_((h4).y), a2, false); \
        a3 = __builtin_amdgcn_fdot2(h2_((wb0).z), h2_((h4).x), a3, false); \
        a3 = __builtin_amdgcn_fdot2(h2_((wb0).w), h2_((h4).y), a3, false); \
        a0 = __builtin_amdgcn_fdot2(h2_((wa1).x), h2_((h4).z), a0, false); \
        a0 = __builtin_amdgcn_fdot2(h2_((wa1).y), h2_((h4).w), a0, false); \
        a1 = __builtin_amdgcn_fdot2(h2_((wa1).z), h2_((h4).z), a1, false); \
        a1 = __builtin_amdgcn_fdot2(h2_((wa1).w), h2_((h4).w), a1, false); \
        a2 = __builtin_amdgcn_fdot2(h2_((wb1).x), h2_((h4).z), a2, false); \
        a2 = __builtin_amdgcn_fdot2(h2_((wb1).y), h2_((h4).w), a2, false); \
        a3 = __builtin_amdgcn_fdot2(h2_((wb1).z), h2_((h4).z), a3, false); \
        a3 = __builtin_amdgcn_fdot2(h2_((wb1).w), h2_((h4).w), a3, false); \
    } while (0)

// LSTM recurrence, weight-persistent, fp16 fdot2, 4-rows/thread k-split,
// pair-wise b128 h broadcasts, lgkm-only step barriers.
// grid: 64 blocks (one per batch) x 512 threads = 8 waves.
__global__ __launch_bounds__(512) void lstm_rec_kernel(
    const float* __restrict__ Ag,      // [B*T][1024] = x@Wih^T + bih + bhh
    const uint4* __restrict__ Wpk,     // this layer's packed fp16 weights
    const float* __restrict__ h0l,     // [B][256] this layer
    const float* __restrict__ c0l,
    float* __restrict__ X, int ldx)    // h output (fp32), row b*T+t
{
    const int b = blockIdx.x;
    const int tid = threadIdx.x;       // 0..511
    const int s = tid >> 8;            // k-half
    const int q = tid & 255;           // row-quad

    __shared__ __align__(16) uint4  Wlh[ULDS * 2 * 512];   // 128 KB
    __shared__ __align__(16) float  gsh2[2 * GATES];       // 8 KB
    __shared__ __align__(16) half_t hsh_h[HT];             // 512 B

    // --- weights into registers (96 VGPRs)
    uint4 wreg[2 * UREG];
    #pragma unroll
    for (int u = 0; u < UREG; u++) {
        wreg[2 * u]     = Wpk[(u * 2 + 0) * 512 + tid];
        wreg[2 * u + 1] = Wpk[(u * 2 + 1) * 512 + tid];
    }
    // --- weights into LDS (once)
    #pragma unroll
    for (int v = 0; v < ULDS; v++) {
        Wlh[(v * 2 + 0) * 512 + tid] = Wpk[((UREG + v) * 2 + 0) * 512 + tid];
        Wlh[(v * 2 + 1) * 512 + tid] = Wpk[((UREG + v) * 2 + 1) * 512 + tid];
    }
    const uint4* __restrict__ Ws = Wpk + (UREG + ULDS) * 2 * 512;

    // --- state init
    if (tid < HT) hsh_h[tid] = (half_t)h0l[b * HT + tid];
    float c = (tid < HT) ? c0l[b * HT + tid] : 0.0f;
    __syncthreads();

    const uint4* hp4 = (const uint4*)hsh_h;  // hp4[16s+p] = halfs h[128s+8p ..+7]
    const int hb = 16 * s;
    const float* AgB = Ag + (int64_t)b * TT * GATES;

    for (int st = 0; st < TT; st++) {
        // Ag: issued early, consumed last (latency hides under the dots)
        float4 aval = make_float4(0.f, 0.f, 0.f, 0.f);
        if (s == 0) aval = *(const float4*)(AgB + (int64_t)st * GATES + 4 * q);

        float a0 = 0.f, a1 = 0.f, a2 = 0.f, a3 = 0.f;

        // streamed pairs first: longest-latency loads issue earliest
        #pragma unroll 2
        for (int p = 0; p < PSTR; p++) {
            uint4 wa0 = Ws[(p * 4 + 0) * 512 + tid];
            uint4 wb0 = Ws[(p * 4 + 1) * 512 + tid];
            uint4 wa1 = Ws[(p * 4 + 2) * 512 + tid];
            uint4 wb1 = Ws[(p * 4 + 3) * 512 + tid];
            uint4 h4  = hp4[hb + PREG + PLDS + p];
            PAIR_DOT(wa0, wb0, wa1, wb1, h4);
        }
        // LDS pairs
        #pragma unroll
        for (int p = 0; p < PLDS; p++) {
            uint4 wa0 = Wlh[(p * 4 + 0) * 512 + tid];
            uint4 wb0 = Wlh[(p * 4 + 1) * 512 + tid];
            uint4 wa1 = Wlh[(p * 4 + 2) * 512 + tid];
            uint4 wb1 = Wlh[(p * 4 + 3) * 512 + tid];
            uint4 h4  = hp4[hb + PREG + p];
            PAIR_DOT(wa0, wb0, wa1, wb1, h4);
        }
        // register pairs
        #pragma unroll
        for (int p = 0; p < PREG; p++) {
            uint4 h4 = hp4[hb + p];
            PAIR_DOT(wreg[4 * p], wreg[4 * p + 1], wreg[4 * p + 2], wreg[4 * p + 3], h4);
        }

        a0 += aval.x; a1 += aval.y; a2 += aval.z; a3 += aval.w;
        *(float4*)&gsh2[s * GATES + 4 * q] = make_float4(a0, a1, a2, a3);
        WG_BARRIER();                          // partial gates visible (lgkm only)

        if (tid < HT) {
            float gi = gsh2[tid]          + gsh2[GATES + tid];
            float gf = gsh2[HT + tid]     + gsh2[GATES + HT + tid];
            float gg = gsh2[2 * HT + tid] + gsh2[GATES + 2 * HT + tid];
            float go = gsh2[3 * HT + tid] + gsh2[GATES + 3 * HT + tid];
            c = fast_sig(gf) * c + fast_sig(gi) * fast_tanh(gg);
            float h = fast_sig(go) * fast_tanh(c);
            X[((int64_t)b * TT + st) * ldx + tid] = h;   // no in-kernel reader
            hsh_h[tid] = (half_t)h;            // safe: dots done at barrier above
        }
        WG_BARRIER();                          // h visible for next step
    }
}

// ---------------------------------------------------------------------------
__global__ __launch_bounds__(256) void softmax512_kernel(float* __restrict__ S)
{
    int row = blockIdx.x * 4 + (threadIdx.x >> 6);
    int lane = threadIdx.x & 63;
    float* p = S + (int64_t)row * 512 + lane * 8;
    float4 v0 = *(float4*)p;
    float4 v1 = *(float4*)(p + 4);
    float m = fmaxf(fmaxf(fmaxf(v0.x, v0.y), fmaxf(v0.z, v0.w)),
                    fmaxf(fmaxf(v1.x, v1.y), fmaxf(v1.z, v1.w)));
    #pragma unroll
    for (int off = 32; off; off >>= 1) m = fmaxf(m, __shfl_xor(m, off));
    v0.x = __expf(v0.x - m); v0.y = __expf(v0.y - m);
    v0.z = __expf(v0.z - m); v0.w = __expf(v0.w - m);
    v1.x = __expf(v1.x - m); v1.y = __expf(v1.y - m);
    v1.z = __expf(v1.z - m); v1.w = __expf(v1.w - m);
    float s = v0.x + v0.y + v0.z + v0.w + v1.x + v1.y + v1.z + v1.w;
    #pragma unroll
    for (int off = 32; off; off >>= 1) s += __shfl_xor(s, off);
    float inv = 1.0f / s;
    v0.x *= inv; v0.y *= inv; v0.z *= inv; v0.w *= inv;
    v1.x *= inv; v1.y *= inv; v1.z *= inv; v1.w *= inv;
    *(float4*)p = v0;
    *(float4*)(p + 4) = v1;
}

__global__ __launch_bounds__(256) void values_kernel(
    const float* __restrict__ Q, const float* __restrict__ L, float* __restrict__ V)
{
    int row = blockIdx.x * 4 + (threadIdx.x >> 6);
    int lane = threadIdx.x & 63;
    float2 q = *(const float2*)(Q + (int64_t)row * OO + lane * 2);
    float2 l = *(const float2*)(L + (int64_t)row * OO + lane * 2);
    float s = q.x * l.x + q.y * l.y;
    #pragma unroll
    for (int off = 32; off; off >>= 1) s += __shfl_xor(s, off);
    if (lane == 0) V[row] = s;
}

// ---------------------------------------------------------------------------
extern "C" void kernel_launch(void* const* d_in, const int* in_sizes, int n_in,
                              void* d_out, int out_size, void* d_ws, size_t ws_size,
                              hipStream_t stream)
{
    const float* enc      = (const float*)d_in[0];
    const float* h0       = (const float*)d_in[1];
    const float* c0       = (const float*)d_in[2];
    const int*   actions  = (const int*)  d_in[3];
    const float* emb_t    = (const float*)d_in[4];
    const float* Wih      = (const float*)d_in[5];
    const float* Whh      = (const float*)d_in[6];
    const float* bih      = (const float*)d_in[7];
    const float* bhh      = (const float*)d_in[8];
    const float* W_attn   = (const float*)d_in[9];
    const float* b_attn   = (const float*)d_in[10];
    const float* W_concat = (const float*)d_in[11];
    const float* b_concat = (const float*)d_in[12];
    const float* W_out    = (const float*)d_in[13];
    const float* W_critic = (const float*)d_in[14];
    const float* b_critic = (const float*)d_in[15];
    (void)in_sizes; (void)n_in; (void)out_size; (void)ws_size;

    const int M = BB * TT;                 // 32768

    float* out    = (float*)d_out;
    float* dact   = out;
    float* logits = out + M;
    float* values = out + M + (int64_t)M * OO;

    // Workspace arena (floats), 256 MiB total:
    //   gates : 33,554,432   (Ag0; later scores then qv)
    //   xbuf  :  8,388,608   (emb -> X1 -> dec)
    //   cat   : 16,777,216   ([out | ctx] row stride 512)
    //   keysR :  8,388,608   (Wpkh during LSTM; keys after)
    float* ws    = (float*)d_ws;
    float* gates = ws;
    float* xbuf  = ws + 33554432;
    float* cat   = ws + 41943040;
    float* keysR = ws + 58720256;
    float* keys  = keysR;
    uint4* Wpkh  = (uint4*)keysR;          // 65536 uint4 = 1 MB; dead before keys
    float* scores = gates;
    float* qv     = gates;
    float* dec    = xbuf;

    const int64_t LWP = 32768;             // uint4s per layer in Wpkh

    // 1) embedding + decoder_action
    hipLaunchKernelGGL(embed_kernel, dim3(M), dim3(256), 0, stream,
                       actions, emb_t, xbuf, dact);
    // 2) repack Whh to fp16 register/LDS/stream layout
    hipLaunchKernelGGL(repack_whh_h_kernel, dim3(256), dim3(256), 0, stream,
                       Whh, Wpkh);
    // 3) layer-0 input GEMM: gates = emb @ Wih0^T + bih0 + bhh0
    hipLaunchKernelGGL((gemm128_kernel<true, 0>), dim3(8, 256, 1), dim3(256), 0, stream,
                       xbuf, Wih, gates, HT, HT, HT, GATES,
                       (int64_t)0, (int64_t)0, (int64_t)0, bih, bhh);
    // 4) layer-0 recurrence -> X1 (xbuf, ldx=256)
    hipLaunchKernelGGL(lstm_rec_kernel, dim3(BB), dim3(512), 0, stream,
                       gates, Wpkh, h0, c0, xbuf, HT);
    // 5) layer-1 input GEMM
    hipLaunchKernelGGL((gemm128_kernel<true, 0>), dim3(8, 256, 1), dim3(256), 0, stream,
                       xbuf, Wih + (int64_t)GATES * HT, gates, HT, HT, HT, GATES,
                       (int64_t)0, (int64_t)0, (int64_t)0, bih + GATES, bhh + GATES);
    // 6) layer-1 recurrence -> cat[:, 0:256] (ldx=512)
    hipLaunchKernelGGL(lstm_rec_kernel, dim3(BB), dim3(512), 0, stream,
                       gates, Wpkh + LWP, h0 + BB * HT, c0 + BB * HT, cat, 2 * HT);
    // 7) keys = enc @ W_attn^T + b_attn   (overwrites Wpkh region)
    hipLaunchKernelGGL((gemm128_kernel<true, 0>), dim3(2, 256, 1), dim3(256), 0, stream,
                       enc, W_attn, keys, HT, HT, HT, HT,
                       (int64_t)0, (int64_t)0, (int64_t)0, b_attn, (const float*)nullptr);
    // 8) scores[b] = out[b] @ keys[b]^T
    hipLaunchKernelGGL((gemm128_kernel<true, 0>), dim3(4, 4, BB), dim3(256), 0, stream,
                       cat, keys, scores, HT, 2 * HT, HT, TT,
                       (int64_t)TT * 2 * HT, (int64_t)TT * HT, (int64_t)TT * TT,
                       (const float*)nullptr, (const float*)nullptr);
    // 9) softmax
    hipLaunchKernelGGL(softmax512_kernel, dim3(M / 4), dim3(256), 0, stream, scores);
    // 10) ctx[b] = P[b] @ enc[b] -> cat[:,256:]
    hipLaunchKernelGGL((gemm128_kernel<false, 0>), dim3(2, 4, BB), dim3(256), 0, stream,
                       scores, enc, cat + HT, TT, TT, HT, 2 * HT,
                       (int64_t)TT * TT, (int64_t)TT * HT, (int64_t)TT * 2 * HT,
                       (const float*)nullptr, (const float*)nullptr);
    // 11) dec = tanh(cat @ W_concat^T + b_concat)
    hipLaunchKernelGGL((gemm128_kernel<true, 1>), dim3(2, 256, 1), dim3(256), 0, stream,
                       cat, W_concat, dec, 2 * HT, 2 * HT, 2 * HT, HT,
                       (int64_t)0, (int64_t)0, (int64_t)0, b_concat, (const float*)nullptr);
    // 12) logits = dec @ W_out^T
    hipLaunchKernelGGL((gemm128_kernel<true, 0>), dim3(1, 256, 1), dim3(256), 0, stream,
                       dec, W_out, logits, HT, HT, HT, OO,
                       (int64_t)0, (int64_t)0, (int64_t)0,
                       (const float*)nullptr, (const float*)nullptr);
    // 13) qv = logits @ W_critic^T + b_critic
    hipLaunchKernelGGL((gemm128_kernel<true, 0>), dim3(1, 256, 1), dim3(256), 0, stream,
                       logits, W_critic, qv, OO, OO, OO, OO,
                       (int64_t)0, (int64_t)0, (int64_t)0, b_critic, (const float*)nullptr);
    // 14) values
    hipLaunchKernelGGL(values_kernel, dim3(M / 4), dim3(256), 0, stream,
                       qv, logits, values);
}

// Round 10
// 3186.398 us; speedup vs baseline: 7.9479x; 1.1147x over previous
//
#include <hip/hip_runtime.h>
#include <stdint.h>

// Problem constants
#define BB   64
#define TT   512
#define HT   256
#define OO   128
#define GATES 1024   // 4*H

// lstm weight layout (R8/R9): 512 threads, thread (s=tid>>8, q=tid&255) owns
// gate rows 4q..4q+3 and k in [128s, 128s+128).  Unit = 4 consecutive k;
// processed in PAIRS (8 k) sharing one b128 h broadcast.
#define PREG 6                     // pairs in VGPRs: 12 units = 96 VGPR/lane
#define PLDS 4                     // pairs in LDS: 8 units = 128 KB
#define PSTR 6                     // pairs streamed from L2/step: 192 KB
#define UREG (2*PREG)
#define ULDS (2*PLDS)

typedef _Float16 half_t;
typedef _Float16 half2_t __attribute__((ext_vector_type(2)));
typedef _Float16 f16x8  __attribute__((ext_vector_type(8)));
typedef float    f32x4  __attribute__((ext_vector_type(4)));

__device__ __forceinline__ half2_t h2_(unsigned int x) {
    return __builtin_bit_cast(half2_t, x);
}
// lgkm-only workgroup barrier (R9 win): no vmcnt drain per step.
#define WG_BARRIER() do { __builtin_amdgcn_s_waitcnt(0xC07F); \
                          __builtin_amdgcn_s_barrier(); } while (0)

__device__ __forceinline__ float fast_sig(float x) {
    return __builtin_amdgcn_rcpf(1.0f + __expf(-x));
}
__device__ __forceinline__ float fast_tanh(float x) {
    float t = __expf(2.0f * x);
    return 1.0f - 2.0f * __builtin_amdgcn_rcpf(t + 1.0f);
}

// ---------------------------------------------------------------------------
// Embedding gather + decoder_action output
__global__ __launch_bounds__(256) void embed_kernel(
    const int* __restrict__ actions, const float* __restrict__ emb_table,
    float* __restrict__ X, float* __restrict__ dact)
{
    int row = blockIdx.x;
    int t = row & (TT - 1);
    int id = (t == 0) ? 0 : actions[row - 1];
    X[(int64_t)row * HT + threadIdx.x] = emb_table[(int64_t)id * HT + threadIdx.x];
    if (threadIdx.x == 0) dact[row] = (float)actions[row];
}

// ---------------------------------------------------------------------------
// Repack Whh to fp16 (R8 layout, unit-indexed).
__global__ __launch_bounds__(256) void repack_whh_h_kernel(
    const float* __restrict__ Whh, uint4* __restrict__ Wpkh)
{
    int idx = blockIdx.x * 256 + threadIdx.x;   // 0..65535
    int tid = idx & 511;
    int ab  = (idx >> 9) & 1;
    int u   = (idx >> 10) & 31;
    int l   = idx >> 15;
    int s = tid >> 8, q = tid & 255;
    int r0 = 4 * q + 2 * ab;
    int k  = 128 * s + 4 * u;
    const float* base = Whh + (int64_t)l * (GATES * HT);
    const float4 a = *(const float4*)(base + (int64_t)r0 * HT + k);
    const float4 b = *(const float4*)(base + (int64_t)(r0 + 1) * HT + k);
    half2_t p0 = {(half_t)a.x, (half_t)a.y};
    half2_t p1 = {(half_t)a.z, (half_t)a.w};
    half2_t p2 = {(half_t)b.x, (half_t)b.y};
    half2_t p3 = {(half_t)b.z, (half_t)b.w};
    uint4 o;
    o.x = __builtin_bit_cast(unsigned int, p0);
    o.y = __builtin_bit_cast(unsigned int, p1);
    o.z = __builtin_bit_cast(unsigned int, p2);
    o.w = __builtin_bit_cast(unsigned int, p3);
    Wpkh[idx] = o;
}

// ---------------------------------------------------------------------------
// MFMA fp16 GEMM: C = act( A @ op(B) + bias1 + bias2 ), fp32 in/out.
// TRANS_B: B is [N,K] ldb (dot along k). else B is [K,N] ldb.
// BM=BN=128, BK=32; 256 threads = 4 waves, each owns a 64x64 quadrant
// (4x4 mfma_f32_16x16x32_f16 tiles).  fp32->fp16 conversion in staging.
// LDS rows padded to 40 halfs: fragment b128 reads land 2-way max (free).
// Layouts (verified, cdna_hip_programming §3): A/B frag [m|n]=lane&15,
// k=quad*8+j; C/D col=lane&15, row=quad*4+reg.
template<bool TRANS_B, int ACT>
__global__ __launch_bounds__(256) void mfma_gemm_kernel(
    const float* __restrict__ A, const float* __restrict__ Bm,
    float* __restrict__ C,
    int K, int lda, int ldb, int ldc,
    int64_t sA, int64_t sB, int64_t sC,
    const float* __restrict__ bias1, const float* __restrict__ bias2)
{
    constexpr int BM = 128, BN = 128, BK = 32;
    constexpr int LDT = BK + 8;                  // 40 halfs = 80 B row stride
    __shared__ __align__(16) half_t Asl[BM * LDT];   // 10 KB
    __shared__ __align__(16) half_t Bsl[BN * LDT];   // 10 KB

    const int tid  = threadIdx.x;
    const int wave = tid >> 6;
    const int lane = tid & 63;
    const int wm = (wave & 1) * 64;
    const int wn = (wave >> 1) * 64;
    const int m0 = blockIdx.y * BM;
    const int n0 = blockIdx.x * BN;
    A  += (int64_t)blockIdx.z * sA;
    Bm += (int64_t)blockIdx.z * sB;
    C  += (int64_t)blockIdx.z * sC;

    const int fm = lane & 15;
    const int qd = lane >> 4;

    f32x4 acc[4][4] = {};

    for (int k0 = 0; k0 < K; k0 += BK) {
        // --- stage A (128 x 32 fp32 -> fp16), coalesced 128B per 8 lanes
        #pragma unroll
        for (int i = 0; i < 4; i++) {
            int idx = tid + i * 256;             // 0..1023
            int r  = idx >> 3;                   // 0..127
            int kq = idx & 7;                    // 0..7
            float4 v = *(const float4*)(A + (int64_t)(m0 + r) * lda + k0 + kq * 4);
            half_t* d = &Asl[r * LDT + kq * 4];
            d[0] = (half_t)v.x; d[1] = (half_t)v.y;
            d[2] = (half_t)v.z; d[3] = (half_t)v.w;
        }
        // --- stage B
        if (TRANS_B) {
            #pragma unroll
            for (int i = 0; i < 4; i++) {
                int idx = tid + i * 256;
                int r  = idx >> 3;
                int kq = idx & 7;
                float4 v = *(const float4*)(Bm + (int64_t)(n0 + r) * ldb + k0 + kq * 4);
                half_t* d = &Bsl[r * LDT + kq * 4];
                d[0] = (half_t)v.x; d[1] = (half_t)v.y;
                d[2] = (half_t)v.z; d[3] = (half_t)v.w;
            }
        } else {
            // B[K][N]: read rows of k (coalesced along n), write transposed
            #pragma unroll
            for (int i = 0; i < 4; i++) {
                int idx = tid + i * 256;
                int kk = idx >> 5;               // 0..31
                int nq = idx & 31;               // 0..31 (x4 n)
                float4 v = *(const float4*)(Bm + (int64_t)(k0 + kk) * ldb + n0 + nq * 4);
                Bsl[(nq * 4 + 0) * LDT + kk] = (half_t)v.x;
                Bsl[(nq * 4 + 1) * LDT + kk] = (half_t)v.y;
                Bsl[(nq * 4 + 2) * LDT + kk] = (half_t)v.z;
                Bsl[(nq * 4 + 3) * LDT + kk] = (half_t)v.w;
            }
        }
        __syncthreads();

        f16x8 af[4], bf[4];
        #pragma unroll
        for (int t = 0; t < 4; t++)
            af[t] = *(const f16x8*)&Asl[(wm + t * 16 + fm) * LDT + qd * 8];
        #pragma unroll
        for (int t = 0; t < 4; t++)
            bf[t] = *(const f16x8*)&Bsl[(wn + t * 16 + fm) * LDT + qd * 8];
        #pragma unroll
        for (int mt = 0; mt < 4; mt++)
            #pragma unroll
            for (int nt = 0; nt < 4; nt++)
                acc[mt][nt] = __builtin_amdgcn_mfma_f32_16x16x32_f16(
                                  af[mt], bf[nt], acc[mt][nt], 0, 0, 0);
        __syncthreads();
    }

    // --- epilogue: D col=lane&15, row=qd*4+reg
    #pragma unroll
    for (int nt = 0; nt < 4; nt++) {
        int n = n0 + wn + nt * 16 + fm;
        float bv = 0.0f;
        if (bias1) bv += bias1[n];
        if (bias2) bv += bias2[n];
        #pragma unroll
        for (int mt = 0; mt < 4; mt++) {
            #pragma unroll
            for (int r = 0; r < 4; r++) {
                int m = m0 + wm + mt * 16 + qd * 4 + r;
                float v = acc[mt][nt][r] + bv;
                if (ACT == 1) v = tanhf(v);
                C[(int64_t)m * ldc + n] = v;
            }
        }
    }
}

// ---------------------------------------------------------------------------
// Generic fp32 tiled GEMM (kept for attention + output chain precision).
template<bool TRANS_B, int ACT>
__global__ __launch_bounds__(256) void gemm128_kernel(
    const float* __restrict__ A, const float* __restrict__ Bm,
    float* __restrict__ C,
    int K, int lda, int ldb, int ldc,
    int64_t sA, int64_t sB, int64_t sC,
    const float* __restrict__ bias1, const float* __restrict__ bias2)
{
    constexpr int BM = 128, BN = 128, BK = 16;
    __shared__ __align__(16) float As[BK][BM + 4];
    __shared__ __align__(16) float Bs[BK][BN + 4];

    const int tid = threadIdx.x;
    const int m0 = blockIdx.y * BM;
    const int n0 = blockIdx.x * BN;
    A  += (int64_t)blockIdx.z * sA;
    Bm += (int64_t)blockIdx.z * sB;
    C  += (int64_t)blockIdx.z * sC;

    const int tm = tid & 15;
    const int tn = tid >> 4;

    float acc[8][8] = {};

    for (int k0 = 0; k0 < K; k0 += BK) {
        #pragma unroll
        for (int i = 0; i < 2; i++) {
            int idx = tid + i * 256;
            int ar = idx >> 2;
            int ak = (idx & 3) * 4;
            const float4 v = *(const float4*)(A + (int64_t)(m0 + ar) * lda + k0 + ak);
            As[ak + 0][ar] = v.x; As[ak + 1][ar] = v.y;
            As[ak + 2][ar] = v.z; As[ak + 3][ar] = v.w;
        }
        if (TRANS_B) {
            #pragma unroll
            for (int i = 0; i < 2; i++) {
                int idx = tid + i * 256;
                int br = idx >> 2;
                int bk = (idx & 3) * 4;
                const float4 v = *(const float4*)(Bm + (int64_t)(n0 + br) * ldb + k0 + bk);
                Bs[bk + 0][br] = v.x; Bs[bk + 1][br] = v.y;
                Bs[bk + 2][br] = v.z; Bs[bk + 3][br] = v.w;
            }
        } else {
            #pragma unroll
            for (int i = 0; i < 2; i++) {
                int idx = tid + i * 256;
                int bk = idx >> 5;
                int bn = (idx & 31) * 4;
                const float4 v = *(const float4*)(Bm + (int64_t)(k0 + bk) * ldb + n0 + bn);
                *(float4*)&Bs[bk][bn] = v;
            }
        }
        __syncthreads();

        #pragma unroll
        for (int k = 0; k < BK; k++) {
            float a[8], b[8];
            *(float4*)&a[0] = *(const float4*)&As[k][tm * 8];
            *(float4*)&a[4] = *(const float4*)&As[k][tm * 8 + 4];
            *(float4*)&b[0] = *(const float4*)&Bs[k][tn * 8];
            *(float4*)&b[4] = *(const float4*)&Bs[k][tn * 8 + 4];
            #pragma unroll
            for (int i = 0; i < 8; i++)
                #pragma unroll
                for (int j = 0; j < 8; j++)
                    acc[i][j] += a[i] * b[j];
        }
        __syncthreads();
    }

    float bv[8];
    #pragma unroll
    for (int j = 0; j < 8; j++) {
        int n = n0 + tn * 8 + j;
        float b = 0.0f;
        if (bias1) b += bias1[n];
        if (bias2) b += bias2[n];
        bv[j] = b;
    }
    #pragma unroll
    for (int i = 0; i < 8; i++) {
        int64_t m = m0 + tm * 8 + i;
        float o[8];
        #pragma unroll
        for (int j = 0; j < 8; j++) {
            float v = acc[i][j] + bv[j];
            if (ACT == 1) v = tanhf(v);
            o[j] = v;
        }
        *(float4*)(C + m * ldc + n0 + tn * 8)     = make_float4(o[0], o[1], o[2], o[3]);
        *(float4*)(C + m * ldc + n0 + tn * 8 + 4) = make_float4(o[4], o[5], o[6], o[7]);
    }
}

// ---------------------------------------------------------------------------
#define PAIR_DOT(wa0, wb0, wa1, wb1, h4)                                  \
    do {                                                                   \
        a0 = __builtin_amdgcn_fdot2(h2_((wa0).x), h2_((h4).x), a0, false); \
        a0 = __builtin_amdgcn_fdot2(h2_((wa0).y), h2_((h4).y), a0, false); \
        a1 = __builtin_amdgcn_fdot2(h2_((wa0).z), h2_((h4).x), a1, false); \
        a1 = __builtin_amdgcn_fdot2(h2_((wa0).w), h2_((h4).y), a1, false); \
        a2 = __builtin_amdgcn_fdot2(h2_((wb0).x), h2_((h4).x), a2, false); \
        a2 = __builtin_amdgcn_fdot2(h2_((wb0).y), h2_((h4).y), a2, false); \
        a3 = __builtin_amdgcn_fdot2(h2_((wb0).z), h2_((h4).x), a3, false); \
        a3 = __builtin_amdgcn_fdot2(h2_((wb0).w), h2_((h4).y), a3, false); \
        a0 = __builtin_amdgcn_fdot2(h2_((wa1).x), h2_((h4).z), a0, false); \
        a0 = __builtin_amdgcn_fdot2(h2_((wa1).y), h2_((h4).w), a0, false); \
        a1 = __builtin_amdgcn_fdot2(h2_((wa1).z), h2_((h4).z), a1, false); \
        a1 = __builtin_amdgcn_fdot2(h2_((wa1).w), h2_((h4).w), a1, false); \
        a2 = __builtin_amdgcn_fdot2(h2_((wb1).x), h2_((h4).z), a2, false); \
        a2 = __builtin_amdgcn_fdot2(h2_((wb1).y), h2_((h4).w), a2, false); \
        a3 = __builtin_amdgcn_fdot2(h2_((wb1).z), h2_((h4).z), a3, false); \
        a3 = __builtin_amdgcn_fdot2(h2_((wb1).w), h2_((h4).w), a3, false); \
    } while (0)

// LSTM recurrence (R9 structure, unchanged): weight-persistent, fp16 fdot2,
// 4-rows/thread k-split, pair-wise b128 h broadcasts, lgkm-only barriers.
__global__ __launch_bounds__(512) void lstm_rec_kernel(
    const float* __restrict__ Ag,
    const uint4* __restrict__ Wpk,
    const float* __restrict__ h0l,
    const float* __restrict__ c0l,
    float* __restrict__ X, int ldx)
{
    const int b = blockIdx.x;
    const int tid = threadIdx.x;
    const int s = tid >> 8;
    const int q = tid & 255;

    __shared__ __align__(16) uint4  Wlh[ULDS * 2 * 512];   // 128 KB
    __shared__ __align__(16) float  gsh2[2 * GATES];       // 8 KB
    __shared__ __align__(16) half_t hsh_h[HT];             // 512 B

    uint4 wreg[2 * UREG];
    #pragma unroll
    for (int u = 0; u < UREG; u++) {
        wreg[2 * u]     = Wpk[(u * 2 + 0) * 512 + tid];
        wreg[2 * u + 1] = Wpk[(u * 2 + 1) * 512 + tid];
    }
    #pragma unroll
    for (int v = 0; v < ULDS; v++) {
        Wlh[(v * 2 + 0) * 512 + tid] = Wpk[((UREG + v) * 2 + 0) * 512 + tid];
        Wlh[(v * 2 + 1) * 512 + tid] = Wpk[((UREG + v) * 2 + 1) * 512 + tid];
    }
    const uint4* __restrict__ Ws = Wpk + (UREG + ULDS) * 2 * 512;

    if (tid < HT) hsh_h[tid] = (half_t)h0l[b * HT + tid];
    float c = (tid < HT) ? c0l[b * HT + tid] : 0.0f;
    __syncthreads();

    const uint4* hp4 = (const uint4*)hsh_h;
    const int hb = 16 * s;
    const float* AgB = Ag + (int64_t)b * TT * GATES;

    for (int st = 0; st < TT; st++) {
        float4 aval = make_float4(0.f, 0.f, 0.f, 0.f);
        if (s == 0) aval = *(const float4*)(AgB + (int64_t)st * GATES + 4 * q);

        float a0 = 0.f, a1 = 0.f, a2 = 0.f, a3 = 0.f;

        #pragma unroll 2
        for (int p = 0; p < PSTR; p++) {
            uint4 wa0 = Ws[(p * 4 + 0) * 512 + tid];
            uint4 wb0 = Ws[(p * 4 + 1) * 512 + tid];
            uint4 wa1 = Ws[(p * 4 + 2) * 512 + tid];
            uint4 wb1 = Ws[(p * 4 + 3) * 512 + tid];
            uint4 h4  = hp4[hb + PREG + PLDS + p];
            PAIR_DOT(wa0, wb0, wa1, wb1, h4);
        }
        #pragma unroll
        for (int p = 0; p < PLDS; p++) {
            uint4 wa0 = Wlh[(p * 4 + 0) * 512 + tid];
            uint4 wb0 = Wlh[(p * 4 + 1) * 512 + tid];
            uint4 wa1 = Wlh[(p * 4 + 2) * 512 + tid];
            uint4 wb1 = Wlh[(p * 4 + 3) * 512 + tid];
            uint4 h4  = hp4[hb + PREG + p];
            PAIR_DOT(wa0, wb0, wa1, wb1, h4);
        }
        #pragma unroll
        for (int p = 0; p < PREG; p++) {
            uint4 h4 = hp4[hb + p];
            PAIR_DOT(wreg[4 * p], wreg[4 * p + 1], wreg[4 * p + 2], wreg[4 * p + 3], h4);
        }

        a0 += aval.x; a1 += aval.y; a2 += aval.z; a3 += aval.w;
        *(float4*)&gsh2[s * GATES + 4 * q] = make_float4(a0, a1, a2, a3);
        WG_BARRIER();

        if (tid < HT) {
            float gi = gsh2[tid]          + gsh2[GATES + tid];
            float gf = gsh2[HT + tid]     + gsh2[GATES + HT + tid];
            float gg = gsh2[2 * HT + tid] + gsh2[GATES + 2 * HT + tid];
            float go = gsh2[3 * HT + tid] + gsh2[GATES + 3 * HT + tid];
            c = fast_sig(gf) * c + fast_sig(gi) * fast_tanh(gg);
            float h = fast_sig(go) * fast_tanh(c);
            X[((int64_t)b * TT + st) * ldx + tid] = h;
            hsh_h[tid] = (half_t)h;
        }
        WG_BARRIER();
    }
}

// ---------------------------------------------------------------------------
__global__ __launch_bounds__(256) void softmax512_kernel(float* __restrict__ S)
{
    int row = blockIdx.x * 4 + (threadIdx.x >> 6);
    int lane = threadIdx.x & 63;
    float* p = S + (int64_t)row * 512 + lane * 8;
    float4 v0 = *(float4*)p;
    float4 v1 = *(float4*)(p + 4);
    float m = fmaxf(fmaxf(fmaxf(v0.x, v0.y), fmaxf(v0.z, v0.w)),
                    fmaxf(fmaxf(v1.x, v1.y), fmaxf(v1.z, v1.w)));
    #pragma unroll
    for (int off = 32; off; off >>= 1) m = fmaxf(m, __shfl_xor(m, off));
    v0.x = __expf(v0.x - m); v0.y = __expf(v0.y - m);
    v0.z = __expf(v0.z - m); v0.w = __expf(v0.w - m);
    v1.x = __expf(v1.x - m); v1.y = __expf(v1.y - m);
    v1.z = __expf(v1.z - m); v1.w = __expf(v1.w - m);
    float s = v0.x + v0.y + v0.z + v0.w + v1.x + v1.y + v1.z + v1.w;
    #pragma unroll
    for (int off = 32; off; off >>= 1) s += __shfl_xor(s, off);
    float inv = 1.0f / s;
    v0.x *= inv; v0.y *= inv; v0.z *= inv; v0.w *= inv;
    v1.x *= inv; v1.y *= inv; v1.z *= inv; v1.w *= inv;
    *(float4*)p = v0;
    *(float4*)(p + 4) = v1;
}

__global__ __launch_bounds__(256) void values_kernel(
    const float* __restrict__ Q, const float* __restrict__ L, float* __restrict__ V)
{
    int row = blockIdx.x * 4 + (threadIdx.x >> 6);
    int lane = threadIdx.x & 63;
    float2 q = *(const float2*)(Q + (int64_t)row * OO + lane * 2);
    float2 l = *(const float2*)(L + (int64_t)row * OO + lane * 2);
    float s = q.x * l.x + q.y * l.y;
    #pragma unroll
    for (int off = 32; off; off >>= 1) s += __shfl_xor(s, off);
    if (lane == 0) V[row] = s;
}

// ---------------------------------------------------------------------------
extern "C" void kernel_launch(void* const* d_in, const int* in_sizes, int n_in,
                              void* d_out, int out_size, void* d_ws, size_t ws_size,
                              hipStream_t stream)
{
    const float* enc      = (const float*)d_in[0];
    const float* h0       = (const float*)d_in[1];
    const float* c0       = (const float*)d_in[2];
    const int*   actions  = (const int*)  d_in[3];
    const float* emb_t    = (const float*)d_in[4];
    const float* Wih      = (const float*)d_in[5];
    const float* Whh      = (const float*)d_in[6];
    const float* bih      = (const float*)d_in[7];
    const float* bhh      = (const float*)d_in[8];
    const float* W_attn   = (const float*)d_in[9];
    const float* b_attn   = (const float*)d_in[10];
    const float* W_concat = (const float*)d_in[11];
    const float* b_concat = (const float*)d_in[12];
    const float* W_out    = (const float*)d_in[13];
    const float* W_critic = (const float*)d_in[14];
    const float* b_critic = (const float*)d_in[15];
    (void)in_sizes; (void)n_in; (void)out_size; (void)ws_size;

    const int M = BB * TT;                 // 32768

    float* out    = (float*)d_out;
    float* dact   = out;
    float* logits = out + M;
    float* values = out + M + (int64_t)M * OO;

    float* ws    = (float*)d_ws;
    float* gates = ws;
    float* xbuf  = ws + 33554432;
    float* cat   = ws + 41943040;
    float* keysR = ws + 58720256;
    float* keys  = keysR;
    uint4* Wpkh  = (uint4*)keysR;          // 1 MB; dead before keys
    float* scores = gates;
    float* qv     = gates;
    float* dec    = xbuf;

    const int64_t LWP = 32768;             // uint4s per layer in Wpkh
    const int64_t LW  = (int64_t)GATES * HT;

    // 1) embedding + decoder_action
    hipLaunchKernelGGL(embed_kernel, dim3(M), dim3(256), 0, stream,
                       actions, emb_t, xbuf, dact);
    // 2) repack Whh to fp16 register/LDS/stream layout
    hipLaunchKernelGGL(repack_whh_h_kernel, dim3(256), dim3(256), 0, stream,
                       Whh, Wpkh);
    // 3) layer-0 input GEMM (MFMA fp16): gates = emb @ Wih0^T + bih0 + bhh0
    hipLaunchKernelGGL((mfma_gemm_kernel<true, 0>), dim3(8, 256, 1), dim3(256), 0, stream,
                       xbuf, Wih, gates, HT, HT, HT, GATES,
                       (int64_t)0, (int64_t)0, (int64_t)0, bih, bhh);
    // 4) layer-0 recurrence -> X1 (xbuf, ldx=256)
    hipLaunchKernelGGL(lstm_rec_kernel, dim3(BB), dim3(512), 0, stream,
                       gates, Wpkh, h0, c0, xbuf, HT);
    // 5) layer-1 input GEMM (MFMA fp16)
    hipLaunchKernelGGL((mfma_gemm_kernel<true, 0>), dim3(8, 256, 1), dim3(256), 0, stream,
                       xbuf, Wih + LW, gates, HT, HT, HT, GATES,
                       (int64_t)0, (int64_t)0, (int64_t)0, bih + GATES, bhh + GATES);
    // 6) layer-1 recurrence -> cat[:, 0:256] (ldx=512)
    hipLaunchKernelGGL(lstm_rec_kernel, dim3(BB), dim3(512), 0, stream,
                       gates, Wpkh + LWP, h0 + BB * HT, c0 + BB * HT, cat, 2 * HT);
    // 7) keys = enc @ W_attn^T + b_attn (MFMA fp16; overwrites Wpkh region)
    hipLaunchKernelGGL((mfma_gemm_kernel<true, 0>), dim3(2, 256, 1), dim3(256), 0, stream,
                       enc, W_attn, keys, HT, HT, HT, HT,
                       (int64_t)0, (int64_t)0, (int64_t)0, b_attn, (const float*)nullptr);
    // 8) scores[b] = out[b] @ keys[b]^T  (fp32, precision-sensitive softmax input)
    hipLaunchKernelGGL((gemm128_kernel<true, 0>), dim3(4, 4, BB), dim3(256), 0, stream,
                       cat, keys, scores, HT, 2 * HT, HT, TT,
                       (int64_t)TT * 2 * HT, (int64_t)TT * HT, (int64_t)TT * TT,
                       (const float*)nullptr, (const float*)nullptr);
    // 9) softmax
    hipLaunchKernelGGL(softmax512_kernel, dim3(M / 4), dim3(256), 0, stream, scores);
    // 10) ctx[b] = P[b] @ enc[b] -> cat[:,256:]  (fp32)
    hipLaunchKernelGGL((gemm128_kernel<false, 0>), dim3(2, 4, BB), dim3(256), 0, stream,
                       scores, enc, cat + HT, TT, TT, HT, 2 * HT,
                       (int64_t)TT * TT, (int64_t)TT * HT, (int64_t)TT * 2 * HT,
                       (const float*)nullptr, (const float*)nullptr);
    // 11) dec = tanh(cat @ W_concat^T + b_concat) (MFMA fp16)
    hipLaunchKernelGGL((mfma_gemm_kernel<true, 1>), dim3(2, 256, 1), dim3(256), 0, stream,
                       cat, W_concat, dec, 2 * HT, 2 * HT, 2 * HT, HT,
                       (int64_t)0, (int64_t)0, (int64_t)0, b_concat, (const float*)nullptr);
    // 12) logits = dec @ W_out^T  (fp32 — output path)
    hipLaunchKernelGGL((gemm128_kernel<true, 0>), dim3(1, 256, 1), dim3(256), 0, stream,
                       dec, W_out, logits, HT, HT, HT, OO,
                       (int64_t)0, (int64_t)0, (int64_t)0,
                       (const float*)nullptr, (const float*)nullptr);
    // 13) qv = logits @ W_critic^T + b_critic  (fp32 — output path)
    hipLaunchKernelGGL((gemm128_kernel<true, 0>), dim3(1, 256, 1), dim3(256), 0, stream,
                       logits, W_critic, qv, OO, OO, OO, OO,
                       (int64_t)0, (int64_t)0, (int64_t)0, b_critic, (const float*)nullptr);
    // 14) values
    hipLaunchKernelGGL(values_kernel, dim3(M / 4), dim3(256), 0, stream,
                       qv, logits, values);
}